// Round 7
// baseline (519.059 us; speedup 1.0000x reference)
//
#include <hip/hip_runtime.h>
#include <math.h>

namespace {

constexpr int NN = 100000;   // nodes
constexpr int NE = 1200000;  // edges
constexpr int NH = 10000;    // hyperedges
constexpr int NI = 1200000;  // incidences
constexpr int D  = 64;       // hidden dim
constexpr int C  = 40;       // classes

constexpr int OFF_H = NN;         // hyperedge rowptr offset
constexpr int OFF_N = NN + NH;    // node-incidence rowptr offset
constexpr int NT    = NN + NH + NN;

// bucket sort: rel0 = edges by dst, rel1 = incid by hyperedge, rel2 = incid by node
constexpr int NBLK   = 150;                 // partition blocks per relation
constexpr int CHUNK  = 8000;                // NI / NBLK (exact)
constexpr int NBUK1  = 196;                 // ceil(100000 / 512)
constexpr int NBUK2  = 157;                 // ceil(10000 / 64)
constexpr int NBUK3  = 196;
constexpr int NBUKT  = NBUK1 + NBUK2 + NBUK3;  // 549
constexpr int CAP    = 10240;               // slack region per bucket

using u16 = unsigned short;
using u32 = unsigned int;

__device__ __forceinline__ float bf2f(u16 u) {
    u32 v = (u32)u << 16;
    return __builtin_bit_cast(float, v);
}
__device__ __forceinline__ u16 f2bf(float f) {
    u32 u = __builtin_bit_cast(u32, f);
    return (u16)((u + 0x7FFFu + ((u >> 16) & 1u)) >> 16);
}
__device__ __forceinline__ u32 pack2(float a, float b) {
    return (u32)f2bf(a) | ((u32)f2bf(b) << 16);
}

// ---- BUILD: LDS multisplit -> coalesced per-bucket-run writes -------------

__global__ __launch_bounds__(256) void k_build(const int* __restrict__ esrc,
                                               const int* __restrict__ edst,
                                               const int* __restrict__ hid,
                                               const int* __restrict__ hnode,
                                               int* __restrict__ gcur,
                                               u32* __restrict__ pairs) {
    int rel = blockIdx.x / NBLK, blk = blockIdx.x % NBLK;
    const int *keys, *vals;
    if (rel == 0)      { keys = edst;  vals = esrc;  }
    else if (rel == 1) { keys = hid;   vals = hnode; }
    else               { keys = hnode; vals = hid;   }
    int bukBase = rel == 0 ? 0 : (rel == 1 ? NBUK1 : NBUK1 + NBUK2);
    int nbuk    = rel == 1 ? NBUK2 : NBUK1;
    int shift   = rel == 1 ? 6 : 9;
    int mask    = (1 << shift) - 1;

    __shared__ int h[NBUK1];          // hist, then reused as cursor
    __shared__ int lofs[NBUK1 + 1];   // exclusive scan of hist
    __shared__ int gbase[NBUK1];      // reserved global offset per bucket
    __shared__ u32 stage[CHUNK];      // 32 KB bucket-sorted staging

    int tid = threadIdx.x;
    for (int i = tid; i < nbuk; i += 256) h[i] = 0;
    __syncthreads();

    int start = blk * CHUNK;
    const int4* k4 = reinterpret_cast<const int4*>(keys + start);
    const int4* v4 = reinterpret_cast<const int4*>(vals + start);

    for (int i = tid; i < CHUNK / 4; i += 256) {
        int4 kk = k4[i];
        atomicAdd(&h[kk.x >> shift], 1);
        atomicAdd(&h[kk.y >> shift], 1);
        atomicAdd(&h[kk.z >> shift], 1);
        atomicAdd(&h[kk.w >> shift], 1);
    }
    __syncthreads();

    if (tid < 64) {
        int acc = 0;
        for (int base = 0; base < nbuk; base += 64) {
            int idx = base + tid;
            int v = idx < nbuk ? h[idx] : 0;
            int sc = v;
#pragma unroll
            for (int o = 1; o < 64; o <<= 1) {
                int t = __shfl_up(sc, o, 64);
                if (tid >= o) sc += t;
            }
            if (idx < nbuk) lofs[idx] = acc + sc - v;
            acc += __shfl(sc, 63, 64);
        }
        if (tid == 0) lofs[nbuk] = acc;  // == CHUNK
    }
    __syncthreads();

    for (int i = tid; i < nbuk; i += 256) gbase[i] = atomicAdd(&gcur[bukBase + i], h[i]);
    __syncthreads();
    for (int i = tid; i < nbuk; i += 256) h[i] = lofs[i];
    __syncthreads();

    for (int i = tid; i < CHUNK / 4; i += 256) {
        int4 kk = k4[i];
        int4 vv = v4[i];
        int p0 = atomicAdd(&h[kk.x >> shift], 1);
        stage[p0] = ((u32)(kk.x & mask) << 17) | (u32)vv.x;
        int p1 = atomicAdd(&h[kk.y >> shift], 1);
        stage[p1] = ((u32)(kk.y & mask) << 17) | (u32)vv.y;
        int p2 = atomicAdd(&h[kk.z >> shift], 1);
        stage[p2] = ((u32)(kk.z & mask) << 17) | (u32)vv.z;
        int p3 = atomicAdd(&h[kk.w >> shift], 1);
        stage[p3] = ((u32)(kk.w & mask) << 17) | (u32)vv.w;
    }
    __syncthreads();

    int wid = tid >> 6, lane = tid & 63;
    for (int buk = wid; buk < nbuk; buk += 4) {
        int s0 = lofs[buk], s1 = lofs[buk + 1];
        int gb = gbase[buk];
        u32* dst = pairs + (size_t)(bukBase + buk) * CAP + gb;
        int cnt = s1 - s0;
        if (gb + cnt > CAP) cnt = CAP - gb;  // defensive
        for (int j = lane; j < cnt; j += 64) dst[j] = stage[s0 + j];
    }
}

// ---- P3: per-bucket fine counting sort -> rowptr + colAll + degrees -------

__global__ __launch_bounds__(256) void k_p3(const u32* __restrict__ pairs,
                                            const int* __restrict__ totals,
                                            int* __restrict__ rowptr,
                                            int* __restrict__ colAll,
                                            float* __restrict__ dinv,
                                            float* __restrict__ Binv,
                                            float* __restrict__ Dinv) {
    int g = blockIdx.x;
    int rel, lb;
    if (g < NBUK1)              { rel = 0; lb = g; }
    else if (g < NBUK1 + NBUK2) { rel = 1; lb = g - NBUK1; }
    else                        { rel = 2; lb = g - NBUK1 - NBUK2; }
    int shift   = rel == 1 ? 6 : 9;
    int bpb     = rel == 1 ? 64 : 512;
    int binBase = rel == 0 ? 0 : (rel == 1 ? NN : NN + NH);
    int nbins   = rel == 1 ? NH : NN;
    int keyBase = lb << shift;
    int tid = threadIdx.x;
    int lane = tid & 63, wid = tid >> 6;

    __shared__ int wred[4];
    int partial = 0;
    for (int j = tid; j < g; j += 256) partial += totals[j];
#pragma unroll
    for (int o = 32; o; o >>= 1) partial += __shfl_xor(partial, o, 64);
    if (lane == 0) wred[wid] = partial;
    __syncthreads();
    int e0 = wred[0] + wred[1] + wred[2] + wred[3];
    int cntT = totals[g];
    if (g == NBUKT - 1 && tid == 0) rowptr[NT] = e0 + cntT;

    const u32* pb = pairs + (size_t)g * CAP;

    __shared__ int h[512];
    __shared__ int cur[512];
    __shared__ int wsum[4];
    for (int i = tid; i < 512; i += 256) h[i] = 0;
    __syncthreads();
    for (int i = tid; i < cntT; i += 256)
        atomicAdd(&h[pb[i] >> 17], 1);
    __syncthreads();

    int j0 = 2 * tid;
    int v0 = h[j0], v1 = h[j0 + 1];
    int s = v0 + v1;
    int sc = s;
#pragma unroll
    for (int o = 1; o < 64; o <<= 1) {
        int t = __shfl_up(sc, o, 64);
        if (lane >= o) sc += t;
    }
    if (lane == 63) wsum[wid] = sc;
    __syncthreads();
    int woff = 0;
    for (int w = 0; w < wid; ++w) woff += wsum[w];
    int excl = woff + sc - s;
    cur[j0] = excl;
    cur[j0 + 1] = excl + v0;
    __syncthreads();

    for (int i = tid; i < bpb; i += 256) {
        int bin = keyBase + i;
        if (bin < nbins) {
            rowptr[binBase + bin] = e0 + cur[i];
            int cnt = h[i];
            if (rel == 0)      dinv[bin] = rsqrtf((float)cnt + 1.0f);
            else if (rel == 1) Binv[bin] = cnt > 0 ? 1.0f / (float)cnt : 0.0f;
            else               Dinv[bin] = cnt > 0 ? 1.0f / (float)cnt : 0.0f;
        }
    }
    __syncthreads();

    for (int i = tid; i < cntT; i += 256) {
        u32 p = pb[i];
        int pos = atomicAdd(&cur[p >> 17], 1);
        colAll[e0 + pos] = (int)(p & 0x1FFFFu);
    }
}

// ---- GEMM: Y[r][c] = (sum_k X[r][k] * W[k][c]) * scale?[r] -> bf16 --------

template <int K, bool SCALE, bool INBF>
__global__ __launch_bounds__(256) void k_gemm(const void* __restrict__ Xv,
                                              const float* __restrict__ W,
                                              const float* __restrict__ scale,
                                              u16* __restrict__ Y, int n) {
    __shared__ float4 Wl[D * K / 4];
    for (int i = threadIdx.x; i < D * K / 4; i += 256)
        Wl[i] = reinterpret_cast<const float4*>(W)[i];
    __syncthreads();

    int r = blockIdx.x * 256 + threadIdx.x;
    if (r >= n) return;

    float xr[D];
    if (INBF) {
        const uint4* x4 = reinterpret_cast<const uint4*>((const u16*)Xv + (size_t)r * D);
#pragma unroll
        for (int i = 0; i < D / 8; ++i) {
            uint4 v = x4[i];
            xr[8 * i + 0] = __builtin_bit_cast(float, v.x << 16);
            xr[8 * i + 1] = __builtin_bit_cast(float, v.x & 0xFFFF0000u);
            xr[8 * i + 2] = __builtin_bit_cast(float, v.y << 16);
            xr[8 * i + 3] = __builtin_bit_cast(float, v.y & 0xFFFF0000u);
            xr[8 * i + 4] = __builtin_bit_cast(float, v.z << 16);
            xr[8 * i + 5] = __builtin_bit_cast(float, v.z & 0xFFFF0000u);
            xr[8 * i + 6] = __builtin_bit_cast(float, v.w << 16);
            xr[8 * i + 7] = __builtin_bit_cast(float, v.w & 0xFFFF0000u);
        }
    } else {
        const float4* x4 = reinterpret_cast<const float4*>((const float*)Xv + (size_t)r * D);
#pragma unroll
        for (int i = 0; i < D / 4; ++i) {
            float4 v = x4[i];
            xr[4 * i + 0] = v.x; xr[4 * i + 1] = v.y;
            xr[4 * i + 2] = v.z; xr[4 * i + 3] = v.w;
        }
    }

    float acc[K];
#pragma unroll
    for (int c = 0; c < K; ++c) acc[c] = 0.0f;

#pragma unroll
    for (int k = 0; k < D; ++k) {
        float xv = xr[k];
#pragma unroll
        for (int c4 = 0; c4 < K / 4; ++c4) {
            float4 w = Wl[k * (K / 4) + c4];
            acc[4 * c4 + 0] = fmaf(xv, w.x, acc[4 * c4 + 0]);
            acc[4 * c4 + 1] = fmaf(xv, w.y, acc[4 * c4 + 1]);
            acc[4 * c4 + 2] = fmaf(xv, w.z, acc[4 * c4 + 2]);
            acc[4 * c4 + 3] = fmaf(xv, w.w, acc[4 * c4 + 3]);
        }
    }

    float s = SCALE ? scale[r] : 1.0f;
    uint4* y4 = reinterpret_cast<uint4*>(Y + (size_t)r * K);
#pragma unroll
    for (int j = 0; j < K / 8; ++j) {
        uint4 o;
        o.x = pack2(acc[8 * j + 0] * s, acc[8 * j + 1] * s);
        o.y = pack2(acc[8 * j + 2] * s, acc[8 * j + 3] * s);
        o.z = pack2(acc[8 * j + 4] * s, acc[8 * j + 5] * s);
        o.w = pack2(acc[8 * j + 6] * s, acc[8 * j + 7] * s);
        y4[j] = o;
    }
}

// ---- fused dual GEMM: G4 = XH@W2h ; G2 = (attn(X1,XH,aw)@W2g)*dinv --------

__global__ __launch_bounds__(256) void k_gemm2(const u16* __restrict__ X1,
                                               const u16* __restrict__ XH,
                                               const float* __restrict__ aw,
                                               const float* __restrict__ Wg,
                                               const float* __restrict__ Wh,
                                               const float* __restrict__ scale,
                                               u16* __restrict__ G2,
                                               u16* __restrict__ G4, int n) {
    __shared__ float4 Wgl[D * C / 4];
    __shared__ float4 Whl[D * C / 4];
    __shared__ float awl[2 * D];
    for (int i = threadIdx.x; i < D * C / 4; i += 256) {
        Wgl[i] = reinterpret_cast<const float4*>(Wg)[i];
        Whl[i] = reinterpret_cast<const float4*>(Wh)[i];
    }
    for (int i = threadIdx.x; i < 2 * D; i += 256) awl[i] = aw[i];
    __syncthreads();

    int r = blockIdx.x * 256 + threadIdx.x;
    if (r >= n) return;

    float h[D];
    {
        const uint4* h4 = reinterpret_cast<const uint4*>(XH + (size_t)r * D);
#pragma unroll
        for (int i = 0; i < D / 8; ++i) {
            uint4 u = h4[i];
            h[8 * i + 0] = __builtin_bit_cast(float, u.x << 16);
            h[8 * i + 1] = __builtin_bit_cast(float, u.x & 0xFFFF0000u);
            h[8 * i + 2] = __builtin_bit_cast(float, u.y << 16);
            h[8 * i + 3] = __builtin_bit_cast(float, u.y & 0xFFFF0000u);
            h[8 * i + 4] = __builtin_bit_cast(float, u.z << 16);
            h[8 * i + 5] = __builtin_bit_cast(float, u.z & 0xFFFF0000u);
            h[8 * i + 6] = __builtin_bit_cast(float, u.w << 16);
            h[8 * i + 7] = __builtin_bit_cast(float, u.w & 0xFFFF0000u);
        }
    }

    float acc[C];
#pragma unroll
    for (int c = 0; c < C; ++c) acc[c] = 0.0f;
#pragma unroll
    for (int k = 0; k < D; ++k) {
        float xv = h[k];
#pragma unroll
        for (int c4 = 0; c4 < C / 4; ++c4) {
            float4 w = Whl[k * (C / 4) + c4];
            acc[4 * c4 + 0] = fmaf(xv, w.x, acc[4 * c4 + 0]);
            acc[4 * c4 + 1] = fmaf(xv, w.y, acc[4 * c4 + 1]);
            acc[4 * c4 + 2] = fmaf(xv, w.z, acc[4 * c4 + 2]);
            acc[4 * c4 + 3] = fmaf(xv, w.w, acc[4 * c4 + 3]);
        }
    }
    {
        uint4* y4 = reinterpret_cast<uint4*>(G4 + (size_t)r * C);
#pragma unroll
        for (int j = 0; j < C / 8; ++j) {
            uint4 o;
            o.x = pack2(acc[8 * j + 0], acc[8 * j + 1]);
            o.y = pack2(acc[8 * j + 2], acc[8 * j + 3]);
            o.z = pack2(acc[8 * j + 4], acc[8 * j + 5]);
            o.w = pack2(acc[8 * j + 6], acc[8 * j + 7]);
            y4[j] = o;
        }
    }

    float a[D];
    {
        const uint4* x4 = reinterpret_cast<const uint4*>(X1 + (size_t)r * D);
#pragma unroll
        for (int i = 0; i < D / 8; ++i) {
            uint4 v = x4[i];
            a[8 * i + 0] = __builtin_bit_cast(float, v.x << 16);
            a[8 * i + 1] = __builtin_bit_cast(float, v.x & 0xFFFF0000u);
            a[8 * i + 2] = __builtin_bit_cast(float, v.y << 16);
            a[8 * i + 3] = __builtin_bit_cast(float, v.y & 0xFFFF0000u);
            a[8 * i + 4] = __builtin_bit_cast(float, v.z << 16);
            a[8 * i + 5] = __builtin_bit_cast(float, v.z & 0xFFFF0000u);
            a[8 * i + 6] = __builtin_bit_cast(float, v.w << 16);
            a[8 * i + 7] = __builtin_bit_cast(float, v.w & 0xFFFF0000u);
        }
    }

    float s0 = 0.0f, s1 = 0.0f;
#pragma unroll
    for (int k = 0; k < D; ++k) {
        s0 = fmaf(a[k], awl[2 * k + 0], s0);
        s1 = fmaf(h[k], awl[2 * k + 1], s1);
    }
    float m = fmaxf(s0, s1);
    float e0 = expf(s0 - m), e1 = expf(s1 - m);
    float inv = 1.0f / (e0 + e1);
    float a0 = e0 * inv, a1 = e1 * inv;
#pragma unroll
    for (int k = 0; k < D; ++k) a[k] = a0 * a[k] + a1 * h[k];

#pragma unroll
    for (int c = 0; c < C; ++c) acc[c] = 0.0f;
#pragma unroll
    for (int k = 0; k < D; ++k) {
        float xv = a[k];
#pragma unroll
        for (int c4 = 0; c4 < C / 4; ++c4) {
            float4 w = Wgl[k * (C / 4) + c4];
            acc[4 * c4 + 0] = fmaf(xv, w.x, acc[4 * c4 + 0]);
            acc[4 * c4 + 1] = fmaf(xv, w.y, acc[4 * c4 + 1]);
            acc[4 * c4 + 2] = fmaf(xv, w.z, acc[4 * c4 + 2]);
            acc[4 * c4 + 3] = fmaf(xv, w.w, acc[4 * c4 + 3]);
        }
    }
    float s = scale[r];
    uint4* y4 = reinterpret_cast<uint4*>(G2 + (size_t)r * C);
#pragma unroll
    for (int j = 0; j < C / 8; ++j) {
        uint4 o;
        o.x = pack2(acc[8 * j + 0] * s, acc[8 * j + 1] * s);
        o.y = pack2(acc[8 * j + 2] * s, acc[8 * j + 3] * s);
        o.z = pack2(acc[8 * j + 4] * s, acc[8 * j + 5] * s);
        o.w = pack2(acc[8 * j + 6] * s, acc[8 * j + 7] * s);
        y4[j] = o;
    }
}

// ---- GCN gather+finalize (bf16 sources, f32 acc, 8x unrolled) -------------

template <int K, bool RELU, bool OUTBF>
__global__ void k_gcn_gather(const int* __restrict__ rp, const int* __restrict__ col,
                             const u16* __restrict__ G, const float* __restrict__ dinv,
                             const float* __restrict__ b, void* __restrict__ out, int n) {
    int t = blockIdx.x * blockDim.x + threadIdx.x;
    int i = t >> 6, f = t & 63;
    if (i >= n) return;
    bool act = (K == 64) || (f < K);
    int e0 = __builtin_amdgcn_readfirstlane(rp[i]);
    int e1 = __builtin_amdgcn_readfirstlane(rp[i + 1]);
    float a0 = act ? bf2f(G[(size_t)i * K + f]) : 0.f;  // self loop
    float a1 = 0.f, a2 = 0.f, a3 = 0.f, a4 = 0.f, a5 = 0.f, a6 = 0.f, a7 = 0.f;
    int e = e0;
    for (; e + 8 <= e1; e += 8) {
        int s0 = col[e], s1 = col[e + 1], s2 = col[e + 2], s3 = col[e + 3];
        int s4 = col[e + 4], s5 = col[e + 5], s6 = col[e + 6], s7 = col[e + 7];
        a0 += act ? bf2f(G[(size_t)s0 * K + f]) : 0.f;
        a1 += act ? bf2f(G[(size_t)s1 * K + f]) : 0.f;
        a2 += act ? bf2f(G[(size_t)s2 * K + f]) : 0.f;
        a3 += act ? bf2f(G[(size_t)s3 * K + f]) : 0.f;
        a4 += act ? bf2f(G[(size_t)s4 * K + f]) : 0.f;
        a5 += act ? bf2f(G[(size_t)s5 * K + f]) : 0.f;
        a6 += act ? bf2f(G[(size_t)s6 * K + f]) : 0.f;
        a7 += act ? bf2f(G[(size_t)s7 * K + f]) : 0.f;
    }
    if (e + 4 <= e1) {
        int s0 = col[e], s1 = col[e + 1], s2 = col[e + 2], s3 = col[e + 3];
        a0 += act ? bf2f(G[(size_t)s0 * K + f]) : 0.f;
        a1 += act ? bf2f(G[(size_t)s1 * K + f]) : 0.f;
        a2 += act ? bf2f(G[(size_t)s2 * K + f]) : 0.f;
        a3 += act ? bf2f(G[(size_t)s3 * K + f]) : 0.f;
        e += 4;
    }
    for (; e < e1; ++e) a0 += act ? bf2f(G[(size_t)col[e] * K + f]) : 0.f;
    if (act) {
        float v = dinv[i] * (((a0 + a1) + (a2 + a3)) + ((a4 + a5) + (a6 + a7))) + b[f];
        if (RELU) v = fmaxf(v, 0.0f);
        if (OUTBF) ((u16*)out)[(size_t)i * K + f] = f2bf(v);
        else       ((float*)out)[(size_t)i * K + f] = v;
    }
}

// ---- hyper aggregate (layer 1): Agg[h] = sum_e X1[col[e]]  (f32 out) ------

__global__ void k_hyp_agg(const int* __restrict__ rp, const int* __restrict__ col,
                          const u16* __restrict__ G, float* __restrict__ Agg, int nh) {
    int t = blockIdx.x * blockDim.x + threadIdx.x;
    int i = t >> 6, f = t & 63;
    if (i >= nh) return;
    int e0 = __builtin_amdgcn_readfirstlane(rp[i]);
    int e1 = __builtin_amdgcn_readfirstlane(rp[i + 1]);
    float a0 = 0.f, a1 = 0.f, a2 = 0.f, a3 = 0.f, a4 = 0.f, a5 = 0.f, a6 = 0.f, a7 = 0.f;
    int e = e0;
    for (; e + 8 <= e1; e += 8) {
        int s0 = col[e], s1 = col[e + 1], s2 = col[e + 2], s3 = col[e + 3];
        int s4 = col[e + 4], s5 = col[e + 5], s6 = col[e + 6], s7 = col[e + 7];
        a0 += bf2f(G[(size_t)s0 * D + f]);
        a1 += bf2f(G[(size_t)s1 * D + f]);
        a2 += bf2f(G[(size_t)s2 * D + f]);
        a3 += bf2f(G[(size_t)s3 * D + f]);
        a4 += bf2f(G[(size_t)s4 * D + f]);
        a5 += bf2f(G[(size_t)s5 * D + f]);
        a6 += bf2f(G[(size_t)s6 * D + f]);
        a7 += bf2f(G[(size_t)s7 * D + f]);
    }
    if (e + 4 <= e1) {
        int s0 = col[e], s1 = col[e + 1], s2 = col[e + 2], s3 = col[e + 3];
        a0 += bf2f(G[(size_t)s0 * D + f]);
        a1 += bf2f(G[(size_t)s1 * D + f]);
        a2 += bf2f(G[(size_t)s2 * D + f]);
        a3 += bf2f(G[(size_t)s3 * D + f]);
        e += 4;
    }
    for (; e < e1; ++e) a0 += bf2f(G[(size_t)col[e] * D + f]);
    Agg[(size_t)i * D + f] = ((a0 + a1) + (a2 + a3)) + ((a4 + a5) + (a6 + a7));
}

// ---- hyper phase A (layer 2, K=40, guarded): M[h] = bf16(Binv*sum G4) -----

template <int K>
__global__ void k_hypA(const int* __restrict__ rp, const int* __restrict__ col,
                       const u16* __restrict__ G, const float* __restrict__ Binv,
                       u16* __restrict__ M, int nh) {
    int t = blockIdx.x * blockDim.x + threadIdx.x;
    int i = t >> 6, f = t & 63;
    if (i >= nh) return;
    bool act = (K == 64) || (f < K);
    int e0 = __builtin_amdgcn_readfirstlane(rp[i]);
    int e1 = __builtin_amdgcn_readfirstlane(rp[i + 1]);
    float a0 = 0.f, a1 = 0.f, a2 = 0.f, a3 = 0.f, a4 = 0.f, a5 = 0.f, a6 = 0.f, a7 = 0.f;
    int e = e0;
    for (; e + 8 <= e1; e += 8) {
        int s0 = col[e], s1 = col[e + 1], s2 = col[e + 2], s3 = col[e + 3];
        int s4 = col[e + 4], s5 = col[e + 5], s6 = col[e + 6], s7 = col[e + 7];
        a0 += act ? bf2f(G[(size_t)s0 * K + f]) : 0.f;
        a1 += act ? bf2f(G[(size_t)s1 * K + f]) : 0.f;
        a2 += act ? bf2f(G[(size_t)s2 * K + f]) : 0.f;
        a3 += act ? bf2f(G[(size_t)s3 * K + f]) : 0.f;
        a4 += act ? bf2f(G[(size_t)s4 * K + f]) : 0.f;
        a5 += act ? bf2f(G[(size_t)s5 * K + f]) : 0.f;
        a6 += act ? bf2f(G[(size_t)s6 * K + f]) : 0.f;
        a7 += act ? bf2f(G[(size_t)s7 * K + f]) : 0.f;
    }
    if (e + 4 <= e1) {
        int s0 = col[e], s1 = col[e + 1], s2 = col[e + 2], s3 = col[e + 3];
        a0 += act ? bf2f(G[(size_t)s0 * K + f]) : 0.f;
        a1 += act ? bf2f(G[(size_t)s1 * K + f]) : 0.f;
        a2 += act ? bf2f(G[(size_t)s2 * K + f]) : 0.f;
        a3 += act ? bf2f(G[(size_t)s3 * K + f]) : 0.f;
        e += 4;
    }
    for (; e < e1; ++e) a0 += act ? bf2f(G[(size_t)col[e] * K + f]) : 0.f;
    if (act)
        M[(size_t)i * K + f] =
            f2bf((((a0 + a1) + (a2 + a3)) + ((a4 + a5) + (a6 + a7))) * Binv[i]);
}

// ---- hyper phase B (layer 1): out = relu(Dinv * sum M + b) -> bf16 --------

template <int K, bool RELU, bool OUTBF>
__global__ void k_hypB(const int* __restrict__ rp, const int* __restrict__ col,
                       const u16* __restrict__ M, const float* __restrict__ Dinv,
                       const float* __restrict__ b, void* __restrict__ out, int n) {
    int t = blockIdx.x * blockDim.x + threadIdx.x;
    int i = t >> 6, f = t & 63;
    if (i >= n) return;
    bool act = (K == 64) || (f < K);
    int e0 = __builtin_amdgcn_readfirstlane(rp[i]);
    int e1 = __builtin_amdgcn_readfirstlane(rp[i + 1]);
    float a0 = 0.f, a1 = 0.f, a2 = 0.f, a3 = 0.f, a4 = 0.f, a5 = 0.f, a6 = 0.f, a7 = 0.f;
    int e = e0;
    for (; e + 8 <= e1; e += 8) {
        int s0 = col[e], s1 = col[e + 1], s2 = col[e + 2], s3 = col[e + 3];
        int s4 = col[e + 4], s5 = col[e + 5], s6 = col[e + 6], s7 = col[e + 7];
        a0 += act ? bf2f(M[(size_t)s0 * K + f]) : 0.f;
        a1 += act ? bf2f(M[(size_t)s1 * K + f]) : 0.f;
        a2 += act ? bf2f(M[(size_t)s2 * K + f]) : 0.f;
        a3 += act ? bf2f(M[(size_t)s3 * K + f]) : 0.f;
        a4 += act ? bf2f(M[(size_t)s4 * K + f]) : 0.f;
        a5 += act ? bf2f(M[(size_t)s5 * K + f]) : 0.f;
        a6 += act ? bf2f(M[(size_t)s6 * K + f]) : 0.f;
        a7 += act ? bf2f(M[(size_t)s7 * K + f]) : 0.f;
    }
    if (e + 4 <= e1) {
        int s0 = col[e], s1 = col[e + 1], s2 = col[e + 2], s3 = col[e + 3];
        a0 += act ? bf2f(M[(size_t)s0 * K + f]) : 0.f;
        a1 += act ? bf2f(M[(size_t)s1 * K + f]) : 0.f;
        a2 += act ? bf2f(M[(size_t)s2 * K + f]) : 0.f;
        a3 += act ? bf2f(M[(size_t)s3 * K + f]) : 0.f;
        e += 4;
    }
    for (; e < e1; ++e) a0 += act ? bf2f(M[(size_t)col[e] * K + f]) : 0.f;
    if (act) {
        float v = (((a0 + a1) + (a2 + a3)) + ((a4 + a5) + (a6 + a7))) * Dinv[i] + b[f];
        if (RELU) v = fmaxf(v, 0.0f);
        if (OUTBF) ((u16*)out)[(size_t)i * K + f] = f2bf(v);
        else       ((float*)out)[(size_t)i * K + f] = v;
    }
}

// ---- fused tail: GCN gather + hyper B + attention + log_softmax -> out ----

__global__ void k_tail(const int* __restrict__ rpE, const int* __restrict__ rpN,
                       const int* __restrict__ col, const u16* __restrict__ G2,
                       const u16* __restrict__ M, const float* __restrict__ dinv,
                       const float* __restrict__ Dinv, const float* __restrict__ b2g,
                       const float* __restrict__ b2h, const float* __restrict__ aw,
                       float* __restrict__ out, int n) {
    int t = blockIdx.x * blockDim.x + threadIdx.x;
    int i = t >> 6, f = t & 63;
    if (i >= n) return;
    bool act = f < C;

    // GCN gather over edges (random 80B rows of G2)
    int e0 = __builtin_amdgcn_readfirstlane(rpE[i]);
    int e1 = __builtin_amdgcn_readfirstlane(rpE[i + 1]);
    float a0 = act ? bf2f(G2[(size_t)i * C + f]) : 0.f;  // self loop
    float a1 = 0.f, a2 = 0.f, a3 = 0.f, a4 = 0.f, a5 = 0.f, a6 = 0.f, a7 = 0.f;
    int e = e0;
    for (; e + 8 <= e1; e += 8) {
        int s0 = col[e], s1 = col[e + 1], s2 = col[e + 2], s3 = col[e + 3];
        int s4 = col[e + 4], s5 = col[e + 5], s6 = col[e + 6], s7 = col[e + 7];
        a0 += act ? bf2f(G2[(size_t)s0 * C + f]) : 0.f;
        a1 += act ? bf2f(G2[(size_t)s1 * C + f]) : 0.f;
        a2 += act ? bf2f(G2[(size_t)s2 * C + f]) : 0.f;
        a3 += act ? bf2f(G2[(size_t)s3 * C + f]) : 0.f;
        a4 += act ? bf2f(G2[(size_t)s4 * C + f]) : 0.f;
        a5 += act ? bf2f(G2[(size_t)s5 * C + f]) : 0.f;
        a6 += act ? bf2f(G2[(size_t)s6 * C + f]) : 0.f;
        a7 += act ? bf2f(G2[(size_t)s7 * C + f]) : 0.f;
    }
    for (; e < e1; ++e) a0 += act ? bf2f(G2[(size_t)col[e] * C + f]) : 0.f;
    float x2 = dinv[i] * (((a0 + a1) + (a2 + a3)) + ((a4 + a5) + (a6 + a7))) +
               (act ? b2g[f] : 0.f);

    // hyper gather over incidences (M is 0.8 MB -> cache-resident)
    int h0 = __builtin_amdgcn_readfirstlane(rpN[i]);
    int h1 = __builtin_amdgcn_readfirstlane(rpN[i + 1]);
    float c0 = 0.f, c1 = 0.f, c2 = 0.f, c3 = 0.f;
    e = h0;
    for (; e + 4 <= h1; e += 4) {
        int s0 = col[e], s1 = col[e + 1], s2 = col[e + 2], s3 = col[e + 3];
        c0 += act ? bf2f(M[(size_t)s0 * C + f]) : 0.f;
        c1 += act ? bf2f(M[(size_t)s1 * C + f]) : 0.f;
        c2 += act ? bf2f(M[(size_t)s2 * C + f]) : 0.f;
        c3 += act ? bf2f(M[(size_t)s3 * C + f]) : 0.f;
    }
    for (; e < h1; ++e) c0 += act ? bf2f(M[(size_t)col[e] * C + f]) : 0.f;
    float xh2 = ((c0 + c1) + (c2 + c3)) * Dinv[i] + (act ? b2h[f] : 0.f);

    if (!act) { x2 = 0.f; xh2 = 0.f; }

    // branch attention
    float p0 = act ? x2 * aw[2 * f + 0] : 0.f;
    float p1 = act ? xh2 * aw[2 * f + 1] : 0.f;
#pragma unroll
    for (int o = 32; o; o >>= 1) {
        p0 += __shfl_xor(p0, o, 64);
        p1 += __shfl_xor(p1, o, 64);
    }
    float m = fmaxf(p0, p1);
    float e0f = expf(p0 - m), e1f = expf(p1 - m);
    float inv = 1.0f / (e0f + e1f);
    float v = (e0f * x2 + e1f * xh2) * inv;

    // log_softmax over classes
    float mv = act ? v : -1e30f;
#pragma unroll
    for (int o = 32; o; o >>= 1) mv = fmaxf(mv, __shfl_xor(mv, o, 64));
    float ex = act ? expf(v - mv) : 0.0f;
    float s = ex;
#pragma unroll
    for (int o = 32; o; o >>= 1) s += __shfl_xor(s, o, 64);
    float lse = mv + logf(s);
    if (act) out[(size_t)i * C + f] = v - lse;
}

}  // namespace

extern "C" void kernel_launch(void* const* d_in, const int* in_sizes, int n_in,
                              void* d_out, int out_size, void* d_ws, size_t ws_size,
                              hipStream_t stream) {
    const float* x     = (const float*)d_in[0];
    const int*   ei    = (const int*)d_in[1];
    const int*   esrc  = ei;
    const int*   edst  = ei + NE;
    const int*   hnode = (const int*)d_in[2];
    const int*   hid   = (const int*)d_in[3];
    const float* W1g = (const float*)d_in[4];
    const float* b1g = (const float*)d_in[5];
    const float* W1h = (const float*)d_in[6];
    const float* b1h = (const float*)d_in[7];
    const float* aw1 = (const float*)d_in[8];
    const float* W2g = (const float*)d_in[9];
    const float* b2g = (const float*)d_in[10];
    const float* W2h = (const float*)d_in[11];
    const float* b2h = (const float*)d_in[12];
    const float* aw2 = (const float*)d_in[13];
    float* out = (float*)d_out;

    char* ws = (char*)d_ws;
    size_t off = 0;
    auto alloc = [&](size_t bytes) -> void* {
        void* p = (void*)(ws + off);
        off = (off + bytes + 255) & ~(size_t)255;
        return p;
    };
    float* dinv   = (float*)alloc((size_t)NN * 4);
    float* Binv   = (float*)alloc((size_t)NH * 4);
    float* Dinv   = (float*)alloc((size_t)NN * 4);
    int*   rpAll  = (int*)alloc((size_t)(NT + 1) * 4);
    int*   colAll = (int*)alloc((size_t)(NE + 2 * (size_t)NI) * 4);  // 14.4 MB
    int*   gcur   = (int*)alloc((size_t)NBUKT * 4);
    // union region: pairs slack (22.5 MB, build-time) / A16,X1,XH16 (38.4 MB)
    char*  U      = (char*)alloc((size_t)3 * NN * D * 2);
    u32*   pairs  = (u32*)U;
    u16*   A16    = (u16*)U;                               // also holds G2 (40-wide)
    u16*   X1     = (u16*)(U + (size_t)NN * D * 2);
    u16*   XH16   = (u16*)(U + (size_t)2 * NN * D * 2);
    u16*   M16    = (u16*)alloc((size_t)NH * D * 2);       // 1.28 MB (64- or 40-wide)
    float* Aggf   = (float*)alloc((size_t)NH * D * 4);     // 2.56 MB
    u16*   G4     = (u16*)alloc((size_t)NN * C * 2);       // 8 MB

    const int B = 256;
    int gNN  = (NN + 255) / 256;
    int gNH  = (NH + 255) / 256;
    int gN64 = NN * 64 / 256;          // 25000 blocks, 1 wave per node
    int gH64 = NH * 64 / 256;          // 2500

    // ---- build CSR + degrees ----
    hipMemsetAsync(gcur, 0, (size_t)NBUKT * 4, stream);
    k_build<<<3 * NBLK, B, 0, stream>>>(esrc, edst, hid, hnode, gcur, pairs);
    k_p3<<<NBUKT, B, 0, stream>>>(pairs, gcur, rpAll, colAll, dinv, Binv, Dinv);

    // ---- layer 1 GCN: x1 = relu(dinv*(self + gather) + b1g) ----
    k_gemm<64, true, false><<<gNN, B, 0, stream>>>(x, W1g, dinv, A16, NN);
    k_gcn_gather<64, true, true><<<gN64, B, 0, stream>>>(rpAll, colAll, A16, dinv, b1g, X1, NN);

    // ---- layer 1 hypergraph (aggregate-first): M = (sum X1)@W1h * Binv ----
    k_hyp_agg<<<gH64, B, 0, stream>>>(rpAll + OFF_H, colAll, X1, Aggf, NH);
    k_gemm<64, true, false><<<gNH, B, 0, stream>>>(Aggf, W1h, Binv, M16, NH);
    k_hypB<64, true, true><<<gN64, B, 0, stream>>>(rpAll + OFF_N, colAll, M16, Dinv, b1h, XH16, NN);

    // ---- dual GEMM: G4 = XH16@W2h ; G2 = (attn(X1,XH16)@W2g)*dinv ----
    k_gemm2<<<gNN, B, 0, stream>>>(X1, XH16, aw1, W2g, W2h, dinv, A16, G4, NN);

    // ---- layer 2 hyper phase A (guarded 80B gathers) ----
    k_hypA<40><<<gH64, B, 0, stream>>>(rpAll + OFF_H, colAll, G4, Binv, M16, NH);

    // ---- fused tail: GCN gather + hyper B + attention + lsm -> out ----
    k_tail<<<gN64, B, 0, stream>>>(rpAll, rpAll + OFF_N, colAll, A16, M16, dinv,
                                   Dinv, b2g, b2h, aw2, out, NN);
}

// Round 8
// 427.149 us; speedup vs baseline: 1.2152x; 1.2152x over previous
//
#include <hip/hip_runtime.h>
#include <math.h>

namespace {

constexpr int NN = 100000;   // nodes
constexpr int NE = 1200000;  // edges
constexpr int NH = 10000;    // hyperedges
constexpr int NI = 1200000;  // incidences
constexpr int D  = 64;       // hidden dim
constexpr int C  = 40;       // classes

constexpr int OFF_H = NN;         // hyperedge rowptr offset
constexpr int OFF_N = NN + NH;    // node-incidence rowptr offset
constexpr int NT    = NN + NH + NN;

// bucket sort: rel0 = edges by dst, rel1 = incid by hyperedge, rel2 = incid by node
constexpr int NBLK   = 150;                 // partition blocks per relation
constexpr int CHUNK  = 8000;                // NI / NBLK (exact)
constexpr int NBUK1  = 196;                 // ceil(100000 / 512)
constexpr int NBUK2  = 157;                 // ceil(10000 / 64)
constexpr int NBUK3  = 196;
constexpr int NBUKT  = NBUK1 + NBUK2 + NBUK3;  // 549
constexpr int CAP    = 10240;               // slack region per bucket

using u16 = unsigned short;
using u32 = unsigned int;

__device__ __forceinline__ float bf2f(u16 u) {
    u32 v = (u32)u << 16;
    return __builtin_bit_cast(float, v);
}
__device__ __forceinline__ u16 f2bf(float f) {
    u32 u = __builtin_bit_cast(u32, f);
    return (u16)((u + 0x7FFFu + ((u >> 16) & 1u)) >> 16);
}
__device__ __forceinline__ u32 pack2(float a, float b) {
    return (u32)f2bf(a) | ((u32)f2bf(b) << 16);
}

// ---- BUILD: LDS multisplit -> coalesced per-bucket-run writes -------------

__global__ __launch_bounds__(256) void k_build(const int* __restrict__ esrc,
                                               const int* __restrict__ edst,
                                               const int* __restrict__ hid,
                                               const int* __restrict__ hnode,
                                               int* __restrict__ gcur,
                                               u32* __restrict__ pairs) {
    int rel = blockIdx.x / NBLK, blk = blockIdx.x % NBLK;
    const int *keys, *vals;
    if (rel == 0)      { keys = edst;  vals = esrc;  }
    else if (rel == 1) { keys = hid;   vals = hnode; }
    else               { keys = hnode; vals = hid;   }
    int bukBase = rel == 0 ? 0 : (rel == 1 ? NBUK1 : NBUK1 + NBUK2);
    int nbuk    = rel == 1 ? NBUK2 : NBUK1;
    int shift   = rel == 1 ? 6 : 9;
    int mask    = (1 << shift) - 1;

    __shared__ int h[NBUK1];          // hist, then reused as cursor
    __shared__ int lofs[NBUK1 + 1];   // exclusive scan of hist
    __shared__ int gbase[NBUK1];      // reserved global offset per bucket
    __shared__ u32 stage[CHUNK];      // 32 KB bucket-sorted staging

    int tid = threadIdx.x;
    for (int i = tid; i < nbuk; i += 256) h[i] = 0;
    __syncthreads();

    int start = blk * CHUNK;
    const int4* k4 = reinterpret_cast<const int4*>(keys + start);
    const int4* v4 = reinterpret_cast<const int4*>(vals + start);

    for (int i = tid; i < CHUNK / 4; i += 256) {
        int4 kk = k4[i];
        atomicAdd(&h[kk.x >> shift], 1);
        atomicAdd(&h[kk.y >> shift], 1);
        atomicAdd(&h[kk.z >> shift], 1);
        atomicAdd(&h[kk.w >> shift], 1);
    }
    __syncthreads();

    if (tid < 64) {
        int acc = 0;
        for (int base = 0; base < nbuk; base += 64) {
            int idx = base + tid;
            int v = idx < nbuk ? h[idx] : 0;
            int sc = v;
#pragma unroll
            for (int o = 1; o < 64; o <<= 1) {
                int t = __shfl_up(sc, o, 64);
                if (tid >= o) sc += t;
            }
            if (idx < nbuk) lofs[idx] = acc + sc - v;
            acc += __shfl(sc, 63, 64);
        }
        if (tid == 0) lofs[nbuk] = acc;  // == CHUNK
    }
    __syncthreads();

    for (int i = tid; i < nbuk; i += 256) gbase[i] = atomicAdd(&gcur[bukBase + i], h[i]);
    __syncthreads();
    for (int i = tid; i < nbuk; i += 256) h[i] = lofs[i];
    __syncthreads();

    for (int i = tid; i < CHUNK / 4; i += 256) {
        int4 kk = k4[i];
        int4 vv = v4[i];
        int p0 = atomicAdd(&h[kk.x >> shift], 1);
        stage[p0] = ((u32)(kk.x & mask) << 17) | (u32)vv.x;
        int p1 = atomicAdd(&h[kk.y >> shift], 1);
        stage[p1] = ((u32)(kk.y & mask) << 17) | (u32)vv.y;
        int p2 = atomicAdd(&h[kk.z >> shift], 1);
        stage[p2] = ((u32)(kk.z & mask) << 17) | (u32)vv.z;
        int p3 = atomicAdd(&h[kk.w >> shift], 1);
        stage[p3] = ((u32)(kk.w & mask) << 17) | (u32)vv.w;
    }
    __syncthreads();

    int wid = tid >> 6, lane = tid & 63;
    for (int buk = wid; buk < nbuk; buk += 4) {
        int s0 = lofs[buk], s1 = lofs[buk + 1];
        int gb = gbase[buk];
        u32* dst = pairs + (size_t)(bukBase + buk) * CAP + gb;
        int cnt = s1 - s0;
        if (gb + cnt > CAP) cnt = CAP - gb;  // defensive
        for (int j = lane; j < cnt; j += 64) dst[j] = stage[s0 + j];
    }
}

// ---- P3: per-bucket fine counting sort -> rowptr + colAll + degrees -------

__global__ __launch_bounds__(256) void k_p3(const u32* __restrict__ pairs,
                                            const int* __restrict__ totals,
                                            int* __restrict__ rowptr,
                                            int* __restrict__ colAll,
                                            float* __restrict__ dinv,
                                            float* __restrict__ Binv,
                                            float* __restrict__ Dinv) {
    int g = blockIdx.x;
    int rel, lb;
    if (g < NBUK1)              { rel = 0; lb = g; }
    else if (g < NBUK1 + NBUK2) { rel = 1; lb = g - NBUK1; }
    else                        { rel = 2; lb = g - NBUK1 - NBUK2; }
    int shift   = rel == 1 ? 6 : 9;
    int bpb     = rel == 1 ? 64 : 512;
    int binBase = rel == 0 ? 0 : (rel == 1 ? NN : NN + NH);
    int nbins   = rel == 1 ? NH : NN;
    int keyBase = lb << shift;
    int tid = threadIdx.x;
    int lane = tid & 63, wid = tid >> 6;

    __shared__ int wred[4];
    int partial = 0;
    for (int j = tid; j < g; j += 256) partial += totals[j];
#pragma unroll
    for (int o = 32; o; o >>= 1) partial += __shfl_xor(partial, o, 64);
    if (lane == 0) wred[wid] = partial;
    __syncthreads();
    int e0 = wred[0] + wred[1] + wred[2] + wred[3];
    int cntT = totals[g];
    if (g == NBUKT - 1 && tid == 0) rowptr[NT] = e0 + cntT;

    const u32* pb = pairs + (size_t)g * CAP;

    __shared__ int h[512];
    __shared__ int cur[512];
    __shared__ int wsum[4];
    for (int i = tid; i < 512; i += 256) h[i] = 0;
    __syncthreads();
    for (int i = tid; i < cntT; i += 256)
        atomicAdd(&h[pb[i] >> 17], 1);
    __syncthreads();

    int j0 = 2 * tid;
    int v0 = h[j0], v1 = h[j0 + 1];
    int s = v0 + v1;
    int sc = s;
#pragma unroll
    for (int o = 1; o < 64; o <<= 1) {
        int t = __shfl_up(sc, o, 64);
        if (lane >= o) sc += t;
    }
    if (lane == 63) wsum[wid] = sc;
    __syncthreads();
    int woff = 0;
    for (int w = 0; w < wid; ++w) woff += wsum[w];
    int excl = woff + sc - s;
    cur[j0] = excl;
    cur[j0 + 1] = excl + v0;
    __syncthreads();

    for (int i = tid; i < bpb; i += 256) {
        int bin = keyBase + i;
        if (bin < nbins) {
            rowptr[binBase + bin] = e0 + cur[i];
            int cnt = h[i];
            if (rel == 0)      dinv[bin] = rsqrtf((float)cnt + 1.0f);
            else if (rel == 1) Binv[bin] = cnt > 0 ? 1.0f / (float)cnt : 0.0f;
            else               Dinv[bin] = cnt > 0 ? 1.0f / (float)cnt : 0.0f;
        }
    }
    __syncthreads();

    for (int i = tid; i < cntT; i += 256) {
        u32 p = pb[i];
        int pos = atomicAdd(&cur[p >> 17], 1);
        colAll[e0 + pos] = (int)(p & 0x1FFFFu);
    }
}

// ---- GEMM: Y[r][c] = (sum_k X[r][k] * W[k][c]) * scale?[r] -> bf16 --------

template <int K, bool SCALE, bool INBF>
__global__ __launch_bounds__(256) void k_gemm(const void* __restrict__ Xv,
                                              const float* __restrict__ W,
                                              const float* __restrict__ scale,
                                              u16* __restrict__ Y, int n) {
    __shared__ float4 Wl[D * K / 4];
    for (int i = threadIdx.x; i < D * K / 4; i += 256)
        Wl[i] = reinterpret_cast<const float4*>(W)[i];
    __syncthreads();

    int r = blockIdx.x * 256 + threadIdx.x;
    if (r >= n) return;

    float xr[D];
    if (INBF) {
        const uint4* x4 = reinterpret_cast<const uint4*>((const u16*)Xv + (size_t)r * D);
#pragma unroll
        for (int i = 0; i < D / 8; ++i) {
            uint4 v = x4[i];
            xr[8 * i + 0] = __builtin_bit_cast(float, v.x << 16);
            xr[8 * i + 1] = __builtin_bit_cast(float, v.x & 0xFFFF0000u);
            xr[8 * i + 2] = __builtin_bit_cast(float, v.y << 16);
            xr[8 * i + 3] = __builtin_bit_cast(float, v.y & 0xFFFF0000u);
            xr[8 * i + 4] = __builtin_bit_cast(float, v.z << 16);
            xr[8 * i + 5] = __builtin_bit_cast(float, v.z & 0xFFFF0000u);
            xr[8 * i + 6] = __builtin_bit_cast(float, v.w << 16);
            xr[8 * i + 7] = __builtin_bit_cast(float, v.w & 0xFFFF0000u);
        }
    } else {
        const float4* x4 = reinterpret_cast<const float4*>((const float*)Xv + (size_t)r * D);
#pragma unroll
        for (int i = 0; i < D / 4; ++i) {
            float4 v = x4[i];
            xr[4 * i + 0] = v.x; xr[4 * i + 1] = v.y;
            xr[4 * i + 2] = v.z; xr[4 * i + 3] = v.w;
        }
    }

    float acc[K];
#pragma unroll
    for (int c = 0; c < K; ++c) acc[c] = 0.0f;

#pragma unroll
    for (int k = 0; k < D; ++k) {
        float xv = xr[k];
#pragma unroll
        for (int c4 = 0; c4 < K / 4; ++c4) {
            float4 w = Wl[k * (K / 4) + c4];
            acc[4 * c4 + 0] = fmaf(xv, w.x, acc[4 * c4 + 0]);
            acc[4 * c4 + 1] = fmaf(xv, w.y, acc[4 * c4 + 1]);
            acc[4 * c4 + 2] = fmaf(xv, w.z, acc[4 * c4 + 2]);
            acc[4 * c4 + 3] = fmaf(xv, w.w, acc[4 * c4 + 3]);
        }
    }

    float s = SCALE ? scale[r] : 1.0f;
    uint4* y4 = reinterpret_cast<uint4*>(Y + (size_t)r * K);
#pragma unroll
    for (int j = 0; j < K / 8; ++j) {
        uint4 o;
        o.x = pack2(acc[8 * j + 0] * s, acc[8 * j + 1] * s);
        o.y = pack2(acc[8 * j + 2] * s, acc[8 * j + 3] * s);
        o.z = pack2(acc[8 * j + 4] * s, acc[8 * j + 5] * s);
        o.w = pack2(acc[8 * j + 6] * s, acc[8 * j + 7] * s);
        y4[j] = o;
    }
}

// ---- fused dual GEMM: G4 = XH@W2h ; G2 = (attn(X1,XH,aw)@W2g)*dinv --------

__global__ __launch_bounds__(256) void k_gemm2(const u16* __restrict__ X1,
                                               const u16* __restrict__ XH,
                                               const float* __restrict__ aw,
                                               const float* __restrict__ Wg,
                                               const float* __restrict__ Wh,
                                               const float* __restrict__ scale,
                                               u16* __restrict__ G2,
                                               u16* __restrict__ G4, int n) {
    __shared__ float4 Wgl[D * C / 4];
    __shared__ float4 Whl[D * C / 4];
    __shared__ float awl[2 * D];
    for (int i = threadIdx.x; i < D * C / 4; i += 256) {
        Wgl[i] = reinterpret_cast<const float4*>(Wg)[i];
        Whl[i] = reinterpret_cast<const float4*>(Wh)[i];
    }
    for (int i = threadIdx.x; i < 2 * D; i += 256) awl[i] = aw[i];
    __syncthreads();

    int r = blockIdx.x * 256 + threadIdx.x;
    if (r >= n) return;

    float h[D];
    {
        const uint4* h4 = reinterpret_cast<const uint4*>(XH + (size_t)r * D);
#pragma unroll
        for (int i = 0; i < D / 8; ++i) {
            uint4 u = h4[i];
            h[8 * i + 0] = __builtin_bit_cast(float, u.x << 16);
            h[8 * i + 1] = __builtin_bit_cast(float, u.x & 0xFFFF0000u);
            h[8 * i + 2] = __builtin_bit_cast(float, u.y << 16);
            h[8 * i + 3] = __builtin_bit_cast(float, u.y & 0xFFFF0000u);
            h[8 * i + 4] = __builtin_bit_cast(float, u.z << 16);
            h[8 * i + 5] = __builtin_bit_cast(float, u.z & 0xFFFF0000u);
            h[8 * i + 6] = __builtin_bit_cast(float, u.w << 16);
            h[8 * i + 7] = __builtin_bit_cast(float, u.w & 0xFFFF0000u);
        }
    }

    float acc[C];
#pragma unroll
    for (int c = 0; c < C; ++c) acc[c] = 0.0f;
#pragma unroll
    for (int k = 0; k < D; ++k) {
        float xv = h[k];
#pragma unroll
        for (int c4 = 0; c4 < C / 4; ++c4) {
            float4 w = Whl[k * (C / 4) + c4];
            acc[4 * c4 + 0] = fmaf(xv, w.x, acc[4 * c4 + 0]);
            acc[4 * c4 + 1] = fmaf(xv, w.y, acc[4 * c4 + 1]);
            acc[4 * c4 + 2] = fmaf(xv, w.z, acc[4 * c4 + 2]);
            acc[4 * c4 + 3] = fmaf(xv, w.w, acc[4 * c4 + 3]);
        }
    }
    {
        uint4* y4 = reinterpret_cast<uint4*>(G4 + (size_t)r * C);
#pragma unroll
        for (int j = 0; j < C / 8; ++j) {
            uint4 o;
            o.x = pack2(acc[8 * j + 0], acc[8 * j + 1]);
            o.y = pack2(acc[8 * j + 2], acc[8 * j + 3]);
            o.z = pack2(acc[8 * j + 4], acc[8 * j + 5]);
            o.w = pack2(acc[8 * j + 6], acc[8 * j + 7]);
            y4[j] = o;
        }
    }

    float a[D];
    {
        const uint4* x4 = reinterpret_cast<const uint4*>(X1 + (size_t)r * D);
#pragma unroll
        for (int i = 0; i < D / 8; ++i) {
            uint4 v = x4[i];
            a[8 * i + 0] = __builtin_bit_cast(float, v.x << 16);
            a[8 * i + 1] = __builtin_bit_cast(float, v.x & 0xFFFF0000u);
            a[8 * i + 2] = __builtin_bit_cast(float, v.y << 16);
            a[8 * i + 3] = __builtin_bit_cast(float, v.y & 0xFFFF0000u);
            a[8 * i + 4] = __builtin_bit_cast(float, v.z << 16);
            a[8 * i + 5] = __builtin_bit_cast(float, v.z & 0xFFFF0000u);
            a[8 * i + 6] = __builtin_bit_cast(float, v.w << 16);
            a[8 * i + 7] = __builtin_bit_cast(float, v.w & 0xFFFF0000u);
        }
    }

    float s0 = 0.0f, s1 = 0.0f;
#pragma unroll
    for (int k = 0; k < D; ++k) {
        s0 = fmaf(a[k], awl[2 * k + 0], s0);
        s1 = fmaf(h[k], awl[2 * k + 1], s1);
    }
    float m = fmaxf(s0, s1);
    float e0 = expf(s0 - m), e1 = expf(s1 - m);
    float inv = 1.0f / (e0 + e1);
    float a0 = e0 * inv, a1 = e1 * inv;
#pragma unroll
    for (int k = 0; k < D; ++k) a[k] = a0 * a[k] + a1 * h[k];

#pragma unroll
    for (int c = 0; c < C; ++c) acc[c] = 0.0f;
#pragma unroll
    for (int k = 0; k < D; ++k) {
        float xv = a[k];
#pragma unroll
        for (int c4 = 0; c4 < C / 4; ++c4) {
            float4 w = Wgl[k * (C / 4) + c4];
            acc[4 * c4 + 0] = fmaf(xv, w.x, acc[4 * c4 + 0]);
            acc[4 * c4 + 1] = fmaf(xv, w.y, acc[4 * c4 + 1]);
            acc[4 * c4 + 2] = fmaf(xv, w.z, acc[4 * c4 + 2]);
            acc[4 * c4 + 3] = fmaf(xv, w.w, acc[4 * c4 + 3]);
        }
    }
    float s = scale[r];
    uint4* y4 = reinterpret_cast<uint4*>(G2 + (size_t)r * C);
#pragma unroll
    for (int j = 0; j < C / 8; ++j) {
        uint4 o;
        o.x = pack2(acc[8 * j + 0] * s, acc[8 * j + 1] * s);
        o.y = pack2(acc[8 * j + 2] * s, acc[8 * j + 3] * s);
        o.z = pack2(acc[8 * j + 4] * s, acc[8 * j + 5] * s);
        o.w = pack2(acc[8 * j + 6] * s, acc[8 * j + 7] * s);
        y4[j] = o;
    }
}

// ---- GCN gather+finalize (bf16 sources, f32 acc, 8x unrolled) -------------

template <int K, bool RELU, bool OUTBF>
__global__ void k_gcn_gather(const int* __restrict__ rp, const int* __restrict__ col,
                             const u16* __restrict__ G, const float* __restrict__ dinv,
                             const float* __restrict__ b, void* __restrict__ out, int n) {
    int t = blockIdx.x * blockDim.x + threadIdx.x;
    int i = t >> 6, f = t & 63;
    if (i >= n) return;
    int e0 = __builtin_amdgcn_readfirstlane(rp[i]);
    int e1 = __builtin_amdgcn_readfirstlane(rp[i + 1]);
    float a0 = bf2f(G[(size_t)i * K + f]);  // self loop
    float a1 = 0.f, a2 = 0.f, a3 = 0.f, a4 = 0.f, a5 = 0.f, a6 = 0.f, a7 = 0.f;
    int e = e0;
    for (; e + 8 <= e1; e += 8) {
        int s0 = col[e], s1 = col[e + 1], s2 = col[e + 2], s3 = col[e + 3];
        int s4 = col[e + 4], s5 = col[e + 5], s6 = col[e + 6], s7 = col[e + 7];
        a0 += bf2f(G[(size_t)s0 * K + f]);
        a1 += bf2f(G[(size_t)s1 * K + f]);
        a2 += bf2f(G[(size_t)s2 * K + f]);
        a3 += bf2f(G[(size_t)s3 * K + f]);
        a4 += bf2f(G[(size_t)s4 * K + f]);
        a5 += bf2f(G[(size_t)s5 * K + f]);
        a6 += bf2f(G[(size_t)s6 * K + f]);
        a7 += bf2f(G[(size_t)s7 * K + f]);
    }
    if (e + 4 <= e1) {
        int s0 = col[e], s1 = col[e + 1], s2 = col[e + 2], s3 = col[e + 3];
        a0 += bf2f(G[(size_t)s0 * K + f]);
        a1 += bf2f(G[(size_t)s1 * K + f]);
        a2 += bf2f(G[(size_t)s2 * K + f]);
        a3 += bf2f(G[(size_t)s3 * K + f]);
        e += 4;
    }
    for (; e < e1; ++e) a0 += bf2f(G[(size_t)col[e] * K + f]);
    if ((K == 64) || (f < K)) {
        float v = dinv[i] * (((a0 + a1) + (a2 + a3)) + ((a4 + a5) + (a6 + a7))) + b[f];
        if (RELU) v = fmaxf(v, 0.0f);
        if (OUTBF) ((u16*)out)[(size_t)i * K + f] = f2bf(v);
        else       ((float*)out)[(size_t)i * K + f] = v;
    }
}

// ---- hyper aggregate (layer 1): Agg[h] = sum_e X1[col[e]]  (f32 out) ------

__global__ void k_hyp_agg(const int* __restrict__ rp, const int* __restrict__ col,
                          const u16* __restrict__ G, float* __restrict__ Agg, int nh) {
    int t = blockIdx.x * blockDim.x + threadIdx.x;
    int i = t >> 6, f = t & 63;
    if (i >= nh) return;
    int e0 = __builtin_amdgcn_readfirstlane(rp[i]);
    int e1 = __builtin_amdgcn_readfirstlane(rp[i + 1]);
    float a0 = 0.f, a1 = 0.f, a2 = 0.f, a3 = 0.f, a4 = 0.f, a5 = 0.f, a6 = 0.f, a7 = 0.f;
    int e = e0;
    for (; e + 8 <= e1; e += 8) {
        int s0 = col[e], s1 = col[e + 1], s2 = col[e + 2], s3 = col[e + 3];
        int s4 = col[e + 4], s5 = col[e + 5], s6 = col[e + 6], s7 = col[e + 7];
        a0 += bf2f(G[(size_t)s0 * D + f]);
        a1 += bf2f(G[(size_t)s1 * D + f]);
        a2 += bf2f(G[(size_t)s2 * D + f]);
        a3 += bf2f(G[(size_t)s3 * D + f]);
        a4 += bf2f(G[(size_t)s4 * D + f]);
        a5 += bf2f(G[(size_t)s5 * D + f]);
        a6 += bf2f(G[(size_t)s6 * D + f]);
        a7 += bf2f(G[(size_t)s7 * D + f]);
    }
    if (e + 4 <= e1) {
        int s0 = col[e], s1 = col[e + 1], s2 = col[e + 2], s3 = col[e + 3];
        a0 += bf2f(G[(size_t)s0 * D + f]);
        a1 += bf2f(G[(size_t)s1 * D + f]);
        a2 += bf2f(G[(size_t)s2 * D + f]);
        a3 += bf2f(G[(size_t)s3 * D + f]);
        e += 4;
    }
    for (; e < e1; ++e) a0 += bf2f(G[(size_t)col[e] * D + f]);
    Agg[(size_t)i * D + f] = ((a0 + a1) + (a2 + a3)) + ((a4 + a5) + (a6 + a7));
}

// ---- hyper phase A: M[h] = bf16(Binv[h] * sum_e G[col[e]]) ----------------

template <int K>
__global__ void k_hypA(const int* __restrict__ rp, const int* __restrict__ col,
                       const u16* __restrict__ G, const float* __restrict__ Binv,
                       u16* __restrict__ M, int nh) {
    int t = blockIdx.x * blockDim.x + threadIdx.x;
    int i = t >> 6, f = t & 63;
    if (i >= nh) return;
    int e0 = __builtin_amdgcn_readfirstlane(rp[i]);
    int e1 = __builtin_amdgcn_readfirstlane(rp[i + 1]);
    float a0 = 0.f, a1 = 0.f, a2 = 0.f, a3 = 0.f, a4 = 0.f, a5 = 0.f, a6 = 0.f, a7 = 0.f;
    int e = e0;
    for (; e + 8 <= e1; e += 8) {
        int s0 = col[e], s1 = col[e + 1], s2 = col[e + 2], s3 = col[e + 3];
        int s4 = col[e + 4], s5 = col[e + 5], s6 = col[e + 6], s7 = col[e + 7];
        a0 += bf2f(G[(size_t)s0 * K + f]);
        a1 += bf2f(G[(size_t)s1 * K + f]);
        a2 += bf2f(G[(size_t)s2 * K + f]);
        a3 += bf2f(G[(size_t)s3 * K + f]);
        a4 += bf2f(G[(size_t)s4 * K + f]);
        a5 += bf2f(G[(size_t)s5 * K + f]);
        a6 += bf2f(G[(size_t)s6 * K + f]);
        a7 += bf2f(G[(size_t)s7 * K + f]);
    }
    if (e + 4 <= e1) {
        int s0 = col[e], s1 = col[e + 1], s2 = col[e + 2], s3 = col[e + 3];
        a0 += bf2f(G[(size_t)s0 * K + f]);
        a1 += bf2f(G[(size_t)s1 * K + f]);
        a2 += bf2f(G[(size_t)s2 * K + f]);
        a3 += bf2f(G[(size_t)s3 * K + f]);
        e += 4;
    }
    for (; e < e1; ++e) a0 += bf2f(G[(size_t)col[e] * K + f]);
    if ((K == 64) || (f < K))
        M[(size_t)i * K + f] =
            f2bf((((a0 + a1) + (a2 + a3)) + ((a4 + a5) + (a6 + a7))) * Binv[i]);
}

// ---- hyper phase B: out[i] = relu?(Dinv[i] * sum_e M[col[e]] + b) ---------

template <int K, bool RELU, bool OUTBF>
__global__ void k_hypB(const int* __restrict__ rp, const int* __restrict__ col,
                       const u16* __restrict__ M, const float* __restrict__ Dinv,
                       const float* __restrict__ b, void* __restrict__ out, int n) {
    int t = blockIdx.x * blockDim.x + threadIdx.x;
    int i = t >> 6, f = t & 63;
    if (i >= n) return;
    int e0 = __builtin_amdgcn_readfirstlane(rp[i]);
    int e1 = __builtin_amdgcn_readfirstlane(rp[i + 1]);
    float a0 = 0.f, a1 = 0.f, a2 = 0.f, a3 = 0.f, a4 = 0.f, a5 = 0.f, a6 = 0.f, a7 = 0.f;
    int e = e0;
    for (; e + 8 <= e1; e += 8) {
        int s0 = col[e], s1 = col[e + 1], s2 = col[e + 2], s3 = col[e + 3];
        int s4 = col[e + 4], s5 = col[e + 5], s6 = col[e + 6], s7 = col[e + 7];
        a0 += bf2f(M[(size_t)s0 * K + f]);
        a1 += bf2f(M[(size_t)s1 * K + f]);
        a2 += bf2f(M[(size_t)s2 * K + f]);
        a3 += bf2f(M[(size_t)s3 * K + f]);
        a4 += bf2f(M[(size_t)s4 * K + f]);
        a5 += bf2f(M[(size_t)s5 * K + f]);
        a6 += bf2f(M[(size_t)s6 * K + f]);
        a7 += bf2f(M[(size_t)s7 * K + f]);
    }
    if (e + 4 <= e1) {
        int s0 = col[e], s1 = col[e + 1], s2 = col[e + 2], s3 = col[e + 3];
        a0 += bf2f(M[(size_t)s0 * K + f]);
        a1 += bf2f(M[(size_t)s1 * K + f]);
        a2 += bf2f(M[(size_t)s2 * K + f]);
        a3 += bf2f(M[(size_t)s3 * K + f]);
        e += 4;
    }
    for (; e < e1; ++e) a0 += bf2f(M[(size_t)col[e] * K + f]);
    if ((K == 64) || (f < K)) {
        float v = (((a0 + a1) + (a2 + a3)) + ((a4 + a5) + (a6 + a7))) * Dinv[i] + b[f];
        if (RELU) v = fmaxf(v, 0.0f);
        if (OUTBF) ((u16*)out)[(size_t)i * K + f] = f2bf(v);
        else       ((float*)out)[(size_t)i * K + f] = v;
    }
}

// ---- branch attention (K = 40, bf16 in) + log_softmax -> f32 --------------

__global__ void k_attn_lsm(const u16* __restrict__ X, const u16* __restrict__ Xh,
                           const float* __restrict__ w, float* __restrict__ out, int n) {
    int t = blockIdx.x * blockDim.x + threadIdx.x;
    int node = t >> 6, lane = t & 63;
    if (node >= n) return;
    bool act = lane < C;
    int idx = node * C + lane;
    float xv = act ? bf2f(X[idx]) : 0.0f;
    float hv = act ? bf2f(Xh[idx]) : 0.0f;
    float p0 = act ? xv * w[2 * lane + 0] : 0.0f;
    float p1 = act ? hv * w[2 * lane + 1] : 0.0f;
#pragma unroll
    for (int o = 32; o; o >>= 1) {
        p0 += __shfl_xor(p0, o, 64);
        p1 += __shfl_xor(p1, o, 64);
    }
    float m = fmaxf(p0, p1);
    float e0 = expf(p0 - m), e1 = expf(p1 - m);
    float inv = 1.0f / (e0 + e1);
    float v = (e0 * xv + e1 * hv) * inv;

    float mv = act ? v : -1e30f;
#pragma unroll
    for (int o = 32; o; o >>= 1) mv = fmaxf(mv, __shfl_xor(mv, o, 64));
    float ex = act ? expf(v - mv) : 0.0f;
    float s = ex;
#pragma unroll
    for (int o = 32; o; o >>= 1) s += __shfl_xor(s, o, 64);
    float lse = mv + logf(s);
    if (act) out[idx] = v - lse;
}

}  // namespace

extern "C" void kernel_launch(void* const* d_in, const int* in_sizes, int n_in,
                              void* d_out, int out_size, void* d_ws, size_t ws_size,
                              hipStream_t stream) {
    const float* x     = (const float*)d_in[0];
    const int*   ei    = (const int*)d_in[1];
    const int*   esrc  = ei;
    const int*   edst  = ei + NE;
    const int*   hnode = (const int*)d_in[2];
    const int*   hid   = (const int*)d_in[3];
    const float* W1g = (const float*)d_in[4];
    const float* b1g = (const float*)d_in[5];
    const float* W1h = (const float*)d_in[6];
    const float* b1h = (const float*)d_in[7];
    const float* aw1 = (const float*)d_in[8];
    const float* W2g = (const float*)d_in[9];
    const float* b2g = (const float*)d_in[10];
    const float* W2h = (const float*)d_in[11];
    const float* b2h = (const float*)d_in[12];
    const float* aw2 = (const float*)d_in[13];
    float* out = (float*)d_out;

    char* ws = (char*)d_ws;
    size_t off = 0;
    auto alloc = [&](size_t bytes) -> void* {
        void* p = (void*)(ws + off);
        off = (off + bytes + 255) & ~(size_t)255;
        return p;
    };
    float* dinv   = (float*)alloc((size_t)NN * 4);
    float* Binv   = (float*)alloc((size_t)NH * 4);
    float* Dinv   = (float*)alloc((size_t)NN * 4);
    int*   rpAll  = (int*)alloc((size_t)(NT + 1) * 4);
    int*   colAll = (int*)alloc((size_t)(NE + 2 * (size_t)NI) * 4);  // 14.4 MB
    int*   gcur   = (int*)alloc((size_t)NBUKT * 4);
    // union region: pairs slack (22.5 MB, build-time) / A16,X1,XH16 (38.4 MB)
    char*  U      = (char*)alloc((size_t)3 * NN * D * 2);
    u32*   pairs  = (u32*)U;
    u16*   A16    = (u16*)U;                               // also holds G2 (40-wide)
    u16*   X1     = (u16*)(U + (size_t)NN * D * 2);
    u16*   XH16   = (u16*)(U + (size_t)2 * NN * D * 2);
    u16*   M16    = (u16*)alloc((size_t)NH * D * 2);       // 1.28 MB
    float* Aggf   = (float*)alloc((size_t)NH * D * 4);     // 2.56 MB
    u16*   G4     = (u16*)alloc((size_t)NN * C * 2);       // 8 MB
    u16*   X2b    = (u16*)alloc((size_t)NN * C * 2);       // 8 MB
    u16*   XH2b   = (u16*)alloc((size_t)NN * C * 2);       // 8 MB

    const int B = 256;
    int gNN  = (NN + 255) / 256;
    int gNH  = (NH + 255) / 256;
    int gN64 = NN * 64 / 256;          // 25000 blocks, 1 wave per node
    int gH64 = NH * 64 / 256;          // 2500

    // ---- build CSR + degrees ----
    hipMemsetAsync(gcur, 0, (size_t)NBUKT * 4, stream);
    k_build<<<3 * NBLK, B, 0, stream>>>(esrc, edst, hid, hnode, gcur, pairs);
    k_p3<<<NBUKT, B, 0, stream>>>(pairs, gcur, rpAll, colAll, dinv, Binv, Dinv);

    // ---- layer 1 GCN: x1 = relu(dinv*(self + gather) + b1g) ----
    k_gemm<64, true, false><<<gNN, B, 0, stream>>>(x, W1g, dinv, A16, NN);
    k_gcn_gather<64, true, true><<<gN64, B, 0, stream>>>(rpAll, colAll, A16, dinv, b1g, X1, NN);

    // ---- layer 1 hypergraph (aggregate-first): M = (sum X1)@W1h * Binv ----
    k_hyp_agg<<<gH64, B, 0, stream>>>(rpAll + OFF_H, colAll, X1, Aggf, NH);
    k_gemm<64, true, false><<<gNH, B, 0, stream>>>(Aggf, W1h, Binv, M16, NH);
    k_hypB<64, true, true><<<gN64, B, 0, stream>>>(rpAll + OFF_N, colAll, M16, Dinv, b1h, XH16, NN);

    // ---- dual GEMM: G4 = XH16@W2h ; G2 = (attn(X1,XH16)@W2g)*dinv ----
    k_gemm2<<<gNN, B, 0, stream>>>(X1, XH16, aw1, W2g, W2h, dinv, A16, G4, NN);

    // ---- layer 2 GCN gather (standalone, keeps MLP wide) ----
    k_gcn_gather<40, false, true><<<gN64, B, 0, stream>>>(rpAll, colAll, A16, dinv, b2g, X2b, NN);

    // ---- layer 2 hypergraph ----
    k_hypA<40><<<gH64, B, 0, stream>>>(rpAll + OFF_H, colAll, G4, Binv, M16, NH);
    k_hypB<40, false, true><<<gN64, B, 0, stream>>>(rpAll + OFF_N, colAll, M16, Dinv, b2h, XH2b, NN);

    // ---- attention 2 + log_softmax -> out ----
    k_attn_lsm<<<gN64, B, 0, stream>>>(X2b, XH2b, aw2, out, NN);
}

// Round 9
// 411.224 us; speedup vs baseline: 1.2622x; 1.0387x over previous
//
#include <hip/hip_runtime.h>
#include <math.h>

namespace {

constexpr int NN = 100000;   // nodes
constexpr int NE = 1200000;  // edges
constexpr int NH = 10000;    // hyperedges
constexpr int NI = 1200000;  // incidences
constexpr int D  = 64;       // hidden dim
constexpr int C  = 40;       // classes

constexpr int OFF_H = NN;         // hyperedge rowptr offset
constexpr int OFF_N = NN + NH;    // node-incidence rowptr offset
constexpr int NT    = NN + NH + NN;

// bucket sort: rel0 = edges by dst, rel1 = incid by hyperedge, rel2 = incid by node
constexpr int NBLK   = 150;                 // partition blocks per relation
constexpr int CHUNK  = 8000;                // NI / NBLK (exact)
constexpr int NBUK1  = 196;                 // ceil(100000 / 512)
constexpr int NBUK2  = 157;                 // ceil(10000 / 64)
constexpr int NBUK3  = 196;
constexpr int NBUKT  = NBUK1 + NBUK2 + NBUK3;  // 549
constexpr int CAP    = 10240;               // slack region per bucket

using u16 = unsigned short;
using u32 = unsigned int;

__device__ __forceinline__ float bf2f(u16 u) {
    u32 v = (u32)u << 16;
    return __builtin_bit_cast(float, v);
}
__device__ __forceinline__ u16 f2bf(float f) {
    u32 u = __builtin_bit_cast(u32, f);
    return (u16)((u + 0x7FFFu + ((u >> 16) & 1u)) >> 16);
}
__device__ __forceinline__ u32 pack2(float a, float b) {
    return (u32)f2bf(a) | ((u32)f2bf(b) << 16);
}
__device__ __forceinline__ float bfu32(u32 w, int hi) {
    return __builtin_bit_cast(float, hi ? (w & 0xFFFF0000u) : (w << 16));
}

// ---- BUILD: LDS multisplit -> coalesced per-bucket-run writes -------------

__global__ __launch_bounds__(256) void k_build(const int* __restrict__ esrc,
                                               const int* __restrict__ edst,
                                               const int* __restrict__ hid,
                                               const int* __restrict__ hnode,
                                               int* __restrict__ gcur,
                                               u32* __restrict__ pairs) {
    int rel = blockIdx.x / NBLK, blk = blockIdx.x % NBLK;
    const int *keys, *vals;
    if (rel == 0)      { keys = edst;  vals = esrc;  }
    else if (rel == 1) { keys = hid;   vals = hnode; }
    else               { keys = hnode; vals = hid;   }
    int bukBase = rel == 0 ? 0 : (rel == 1 ? NBUK1 : NBUK1 + NBUK2);
    int nbuk    = rel == 1 ? NBUK2 : NBUK1;
    int shift   = rel == 1 ? 6 : 9;
    int mask    = (1 << shift) - 1;

    __shared__ int h[NBUK1];          // hist, then reused as cursor
    __shared__ int lofs[NBUK1 + 1];   // exclusive scan of hist
    __shared__ int gbase[NBUK1];      // reserved global offset per bucket
    __shared__ u32 stage[CHUNK];      // 32 KB bucket-sorted staging

    int tid = threadIdx.x;
    for (int i = tid; i < nbuk; i += 256) h[i] = 0;
    __syncthreads();

    int start = blk * CHUNK;
    const int4* k4 = reinterpret_cast<const int4*>(keys + start);
    const int4* v4 = reinterpret_cast<const int4*>(vals + start);

    for (int i = tid; i < CHUNK / 4; i += 256) {
        int4 kk = k4[i];
        atomicAdd(&h[kk.x >> shift], 1);
        atomicAdd(&h[kk.y >> shift], 1);
        atomicAdd(&h[kk.z >> shift], 1);
        atomicAdd(&h[kk.w >> shift], 1);
    }
    __syncthreads();

    if (tid < 64) {
        int acc = 0;
        for (int base = 0; base < nbuk; base += 64) {
            int idx = base + tid;
            int v = idx < nbuk ? h[idx] : 0;
            int sc = v;
#pragma unroll
            for (int o = 1; o < 64; o <<= 1) {
                int t = __shfl_up(sc, o, 64);
                if (tid >= o) sc += t;
            }
            if (idx < nbuk) lofs[idx] = acc + sc - v;
            acc += __shfl(sc, 63, 64);
        }
        if (tid == 0) lofs[nbuk] = acc;  // == CHUNK
    }
    __syncthreads();

    for (int i = tid; i < nbuk; i += 256) gbase[i] = atomicAdd(&gcur[bukBase + i], h[i]);
    __syncthreads();
    for (int i = tid; i < nbuk; i += 256) h[i] = lofs[i];
    __syncthreads();

    for (int i = tid; i < CHUNK / 4; i += 256) {
        int4 kk = k4[i];
        int4 vv = v4[i];
        int p0 = atomicAdd(&h[kk.x >> shift], 1);
        stage[p0] = ((u32)(kk.x & mask) << 17) | (u32)vv.x;
        int p1 = atomicAdd(&h[kk.y >> shift], 1);
        stage[p1] = ((u32)(kk.y & mask) << 17) | (u32)vv.y;
        int p2 = atomicAdd(&h[kk.z >> shift], 1);
        stage[p2] = ((u32)(kk.z & mask) << 17) | (u32)vv.z;
        int p3 = atomicAdd(&h[kk.w >> shift], 1);
        stage[p3] = ((u32)(kk.w & mask) << 17) | (u32)vv.w;
    }
    __syncthreads();

    int wid = tid >> 6, lane = tid & 63;
    for (int buk = wid; buk < nbuk; buk += 4) {
        int s0 = lofs[buk], s1 = lofs[buk + 1];
        int gb = gbase[buk];
        u32* dst = pairs + (size_t)(bukBase + buk) * CAP + gb;
        int cnt = s1 - s0;
        if (gb + cnt > CAP) cnt = CAP - gb;  // defensive
        for (int j = lane; j < cnt; j += 64) dst[j] = stage[s0 + j];
    }
}

// ---- P3: per-bucket fine counting sort -> rowptr + colAll + degrees -------

__global__ __launch_bounds__(256) void k_p3(const u32* __restrict__ pairs,
                                            const int* __restrict__ totals,
                                            int* __restrict__ rowptr,
                                            int* __restrict__ colAll,
                                            float* __restrict__ dinv,
                                            float* __restrict__ Binv,
                                            float* __restrict__ Dinv) {
    int g = blockIdx.x;
    int rel, lb;
    if (g < NBUK1)              { rel = 0; lb = g; }
    else if (g < NBUK1 + NBUK2) { rel = 1; lb = g - NBUK1; }
    else                        { rel = 2; lb = g - NBUK1 - NBUK2; }
    int shift   = rel == 1 ? 6 : 9;
    int bpb     = rel == 1 ? 64 : 512;
    int binBase = rel == 0 ? 0 : (rel == 1 ? NN : NN + NH);
    int nbins   = rel == 1 ? NH : NN;
    int keyBase = lb << shift;
    int tid = threadIdx.x;
    int lane = tid & 63, wid = tid >> 6;

    __shared__ int wred[4];
    int partial = 0;
    for (int j = tid; j < g; j += 256) partial += totals[j];
#pragma unroll
    for (int o = 32; o; o >>= 1) partial += __shfl_xor(partial, o, 64);
    if (lane == 0) wred[wid] = partial;
    __syncthreads();
    int e0 = wred[0] + wred[1] + wred[2] + wred[3];
    int cntT = totals[g];
    if (g == NBUKT - 1 && tid == 0) rowptr[NT] = e0 + cntT;

    const u32* pb = pairs + (size_t)g * CAP;

    __shared__ int h[512];
    __shared__ int cur[512];
    __shared__ int wsum[4];
    for (int i = tid; i < 512; i += 256) h[i] = 0;
    __syncthreads();
    for (int i = tid; i < cntT; i += 256)
        atomicAdd(&h[pb[i] >> 17], 1);
    __syncthreads();

    int j0 = 2 * tid;
    int v0 = h[j0], v1 = h[j0 + 1];
    int s = v0 + v1;
    int sc = s;
#pragma unroll
    for (int o = 1; o < 64; o <<= 1) {
        int t = __shfl_up(sc, o, 64);
        if (lane >= o) sc += t;
    }
    if (lane == 63) wsum[wid] = sc;
    __syncthreads();
    int woff = 0;
    for (int w = 0; w < wid; ++w) woff += wsum[w];
    int excl = woff + sc - s;
    cur[j0] = excl;
    cur[j0 + 1] = excl + v0;
    __syncthreads();

    for (int i = tid; i < bpb; i += 256) {
        int bin = keyBase + i;
        if (bin < nbins) {
            rowptr[binBase + bin] = e0 + cur[i];
            int cnt = h[i];
            if (rel == 0)      dinv[bin] = rsqrtf((float)cnt + 1.0f);
            else if (rel == 1) Binv[bin] = cnt > 0 ? 1.0f / (float)cnt : 0.0f;
            else               Dinv[bin] = cnt > 0 ? 1.0f / (float)cnt : 0.0f;
        }
    }
    __syncthreads();

    for (int i = tid; i < cntT; i += 256) {
        u32 p = pb[i];
        int pos = atomicAdd(&cur[p >> 17], 1);
        colAll[e0 + pos] = (int)(p & 0x1FFFFu);
    }
}

// ---- GEMM: Y[r][c] = (sum_k X[r][k] * W[k][c]) * scale?[r] -> bf16 --------

template <int K, bool SCALE, bool INBF>
__global__ __launch_bounds__(256) void k_gemm(const void* __restrict__ Xv,
                                              const float* __restrict__ W,
                                              const float* __restrict__ scale,
                                              u16* __restrict__ Y, int n) {
    __shared__ float4 Wl[D * K / 4];
    for (int i = threadIdx.x; i < D * K / 4; i += 256)
        Wl[i] = reinterpret_cast<const float4*>(W)[i];
    __syncthreads();

    int r = blockIdx.x * 256 + threadIdx.x;
    if (r >= n) return;

    float xr[D];
    if (INBF) {
        const uint4* x4 = reinterpret_cast<const uint4*>((const u16*)Xv + (size_t)r * D);
#pragma unroll
        for (int i = 0; i < D / 8; ++i) {
            uint4 v = x4[i];
            xr[8 * i + 0] = __builtin_bit_cast(float, v.x << 16);
            xr[8 * i + 1] = __builtin_bit_cast(float, v.x & 0xFFFF0000u);
            xr[8 * i + 2] = __builtin_bit_cast(float, v.y << 16);
            xr[8 * i + 3] = __builtin_bit_cast(float, v.y & 0xFFFF0000u);
            xr[8 * i + 4] = __builtin_bit_cast(float, v.z << 16);
            xr[8 * i + 5] = __builtin_bit_cast(float, v.z & 0xFFFF0000u);
            xr[8 * i + 6] = __builtin_bit_cast(float, v.w << 16);
            xr[8 * i + 7] = __builtin_bit_cast(float, v.w & 0xFFFF0000u);
        }
    } else {
        const float4* x4 = reinterpret_cast<const float4*>((const float*)Xv + (size_t)r * D);
#pragma unroll
        for (int i = 0; i < D / 4; ++i) {
            float4 v = x4[i];
            xr[4 * i + 0] = v.x; xr[4 * i + 1] = v.y;
            xr[4 * i + 2] = v.z; xr[4 * i + 3] = v.w;
        }
    }

    float acc[K];
#pragma unroll
    for (int c = 0; c < K; ++c) acc[c] = 0.0f;

#pragma unroll
    for (int k = 0; k < D; ++k) {
        float xv = xr[k];
#pragma unroll
        for (int c4 = 0; c4 < K / 4; ++c4) {
            float4 w = Wl[k * (K / 4) + c4];
            acc[4 * c4 + 0] = fmaf(xv, w.x, acc[4 * c4 + 0]);
            acc[4 * c4 + 1] = fmaf(xv, w.y, acc[4 * c4 + 1]);
            acc[4 * c4 + 2] = fmaf(xv, w.z, acc[4 * c4 + 2]);
            acc[4 * c4 + 3] = fmaf(xv, w.w, acc[4 * c4 + 3]);
        }
    }

    float s = SCALE ? scale[r] : 1.0f;
    uint4* y4 = reinterpret_cast<uint4*>(Y + (size_t)r * K);
#pragma unroll
    for (int j = 0; j < K / 8; ++j) {
        uint4 o;
        o.x = pack2(acc[8 * j + 0] * s, acc[8 * j + 1] * s);
        o.y = pack2(acc[8 * j + 2] * s, acc[8 * j + 3] * s);
        o.z = pack2(acc[8 * j + 4] * s, acc[8 * j + 5] * s);
        o.w = pack2(acc[8 * j + 6] * s, acc[8 * j + 7] * s);
        y4[j] = o;
    }
}

// ---- attention GEMM, two-pass streaming (low VGPR):
//      G2 = (attn(X1,XH,aw) @ W2g) * dinv -> bf16

__global__ __launch_bounds__(256) void k_gemm_attn(const u16* __restrict__ X1,
                                                   const u16* __restrict__ XH,
                                                   const float* __restrict__ aw,
                                                   const float* __restrict__ W,
                                                   const float* __restrict__ scale,
                                                   u16* __restrict__ Y, int n) {
    __shared__ float4 Wl[D * C / 4];
    __shared__ float awl[2 * D];
    for (int i = threadIdx.x; i < D * C / 4; i += 256)
        Wl[i] = reinterpret_cast<const float4*>(W)[i];
    for (int i = threadIdx.x; i < 2 * D; i += 256) awl[i] = aw[i];
    __syncthreads();

    int r = blockIdx.x * 256 + threadIdx.x;
    if (r >= n) return;

    const uint4* x4 = reinterpret_cast<const uint4*>(X1 + (size_t)r * D);
    const uint4* h4 = reinterpret_cast<const uint4*>(XH + (size_t)r * D);

    // pass 1: attention logits (streaming, 2 accumulators)
    float s0 = 0.0f, s1 = 0.0f;
#pragma unroll
    for (int i = 0; i < D / 8; ++i) {
        uint4 v = x4[i];
        uint4 u = h4[i];
#pragma unroll
        for (int j = 0; j < 4; ++j) {
            u32 wv = j == 0 ? v.x : (j == 1 ? v.y : (j == 2 ? v.z : v.w));
            u32 wu = j == 0 ? u.x : (j == 1 ? u.y : (j == 2 ? u.z : u.w));
            int k = 8 * i + 2 * j;
            s0 = fmaf(bfu32(wv, 0), awl[2 * k + 0], s0);
            s0 = fmaf(bfu32(wv, 1), awl[2 * k + 2], s0);
            s1 = fmaf(bfu32(wu, 0), awl[2 * k + 1], s1);
            s1 = fmaf(bfu32(wu, 1), awl[2 * k + 3], s1);
        }
    }
    float m = fmaxf(s0, s1);
    float e0 = expf(s0 - m), e1 = expf(s1 - m);
    float inv = 1.0f / (e0 + e1);
    float a0 = e0 * inv, a1 = e1 * inv;

    // pass 2: blended row -> GEMM (re-stream X1/XH from L2)
    float acc[C];
#pragma unroll
    for (int c = 0; c < C; ++c) acc[c] = 0.0f;
#pragma unroll
    for (int i = 0; i < D / 8; ++i) {
        uint4 v = x4[i];
        uint4 u = h4[i];
#pragma unroll
        for (int j = 0; j < 8; ++j) {
            u32 wv = (j >> 1) == 0 ? v.x : ((j >> 1) == 1 ? v.y : ((j >> 1) == 2 ? v.z : v.w));
            u32 wu = (j >> 1) == 0 ? u.x : ((j >> 1) == 1 ? u.y : ((j >> 1) == 2 ? u.z : u.w));
            float xa = a0 * bfu32(wv, j & 1) + a1 * bfu32(wu, j & 1);
            int k = 8 * i + j;
#pragma unroll
            for (int c4 = 0; c4 < C / 4; ++c4) {
                float4 w = Wl[k * (C / 4) + c4];
                acc[4 * c4 + 0] = fmaf(xa, w.x, acc[4 * c4 + 0]);
                acc[4 * c4 + 1] = fmaf(xa, w.y, acc[4 * c4 + 1]);
                acc[4 * c4 + 2] = fmaf(xa, w.z, acc[4 * c4 + 2]);
                acc[4 * c4 + 3] = fmaf(xa, w.w, acc[4 * c4 + 3]);
            }
        }
    }
    float s = scale[r];
    uint4* y4 = reinterpret_cast<uint4*>(Y + (size_t)r * C);
#pragma unroll
    for (int j = 0; j < C / 8; ++j) {
        uint4 o;
        o.x = pack2(acc[8 * j + 0] * s, acc[8 * j + 1] * s);
        o.y = pack2(acc[8 * j + 2] * s, acc[8 * j + 3] * s);
        o.z = pack2(acc[8 * j + 4] * s, acc[8 * j + 5] * s);
        o.w = pack2(acc[8 * j + 6] * s, acc[8 * j + 7] * s);
        y4[j] = o;
    }
}

// ---- GCN gather+finalize (bf16 sources, f32 acc, 8x unrolled) -------------

template <int K, bool RELU, bool OUTBF>
__global__ void k_gcn_gather(const int* __restrict__ rp, const int* __restrict__ col,
                             const u16* __restrict__ G, const float* __restrict__ dinv,
                             const float* __restrict__ b, void* __restrict__ out, int n) {
    int t = blockIdx.x * blockDim.x + threadIdx.x;
    int i = t >> 6, f = t & 63;
    if (i >= n) return;
    int e0 = __builtin_amdgcn_readfirstlane(rp[i]);
    int e1 = __builtin_amdgcn_readfirstlane(rp[i + 1]);
    float a0 = bf2f(G[(size_t)i * K + f]);  // self loop
    float a1 = 0.f, a2 = 0.f, a3 = 0.f, a4 = 0.f, a5 = 0.f, a6 = 0.f, a7 = 0.f;
    int e = e0;
    for (; e + 8 <= e1; e += 8) {
        int s0 = col[e], s1 = col[e + 1], s2 = col[e + 2], s3 = col[e + 3];
        int s4 = col[e + 4], s5 = col[e + 5], s6 = col[e + 6], s7 = col[e + 7];
        a0 += bf2f(G[(size_t)s0 * K + f]);
        a1 += bf2f(G[(size_t)s1 * K + f]);
        a2 += bf2f(G[(size_t)s2 * K + f]);
        a3 += bf2f(G[(size_t)s3 * K + f]);
        a4 += bf2f(G[(size_t)s4 * K + f]);
        a5 += bf2f(G[(size_t)s5 * K + f]);
        a6 += bf2f(G[(size_t)s6 * K + f]);
        a7 += bf2f(G[(size_t)s7 * K + f]);
    }
    if (e + 4 <= e1) {
        int s0 = col[e], s1 = col[e + 1], s2 = col[e + 2], s3 = col[e + 3];
        a0 += bf2f(G[(size_t)s0 * K + f]);
        a1 += bf2f(G[(size_t)s1 * K + f]);
        a2 += bf2f(G[(size_t)s2 * K + f]);
        a3 += bf2f(G[(size_t)s3 * K + f]);
        e += 4;
    }
    for (; e < e1; ++e) a0 += bf2f(G[(size_t)col[e] * K + f]);
    if ((K == 64) || (f < K)) {
        float v = dinv[i] * (((a0 + a1) + (a2 + a3)) + ((a4 + a5) + (a6 + a7))) + b[f];
        if (RELU) v = fmaxf(v, 0.0f);
        if (OUTBF) ((u16*)out)[(size_t)i * K + f] = f2bf(v);
        else       ((float*)out)[(size_t)i * K + f] = v;
    }
}

// ---- hyper aggregate (layer 1): Agg[h] = sum_e X1[col[e]]  (f32 out) ------

__global__ void k_hyp_agg(const int* __restrict__ rp, const int* __restrict__ col,
                          const u16* __restrict__ G, float* __restrict__ Agg, int nh) {
    int t = blockIdx.x * blockDim.x + threadIdx.x;
    int i = t >> 6, f = t & 63;
    if (i >= nh) return;
    int e0 = __builtin_amdgcn_readfirstlane(rp[i]);
    int e1 = __builtin_amdgcn_readfirstlane(rp[i + 1]);
    float a0 = 0.f, a1 = 0.f, a2 = 0.f, a3 = 0.f, a4 = 0.f, a5 = 0.f, a6 = 0.f, a7 = 0.f;
    int e = e0;
    for (; e + 8 <= e1; e += 8) {
        int s0 = col[e], s1 = col[e + 1], s2 = col[e + 2], s3 = col[e + 3];
        int s4 = col[e + 4], s5 = col[e + 5], s6 = col[e + 6], s7 = col[e + 7];
        a0 += bf2f(G[(size_t)s0 * D + f]);
        a1 += bf2f(G[(size_t)s1 * D + f]);
        a2 += bf2f(G[(size_t)s2 * D + f]);
        a3 += bf2f(G[(size_t)s3 * D + f]);
        a4 += bf2f(G[(size_t)s4 * D + f]);
        a5 += bf2f(G[(size_t)s5 * D + f]);
        a6 += bf2f(G[(size_t)s6 * D + f]);
        a7 += bf2f(G[(size_t)s7 * D + f]);
    }
    if (e + 4 <= e1) {
        int s0 = col[e], s1 = col[e + 1], s2 = col[e + 2], s3 = col[e + 3];
        a0 += bf2f(G[(size_t)s0 * D + f]);
        a1 += bf2f(G[(size_t)s1 * D + f]);
        a2 += bf2f(G[(size_t)s2 * D + f]);
        a3 += bf2f(G[(size_t)s3 * D + f]);
        e += 4;
    }
    for (; e < e1; ++e) a0 += bf2f(G[(size_t)col[e] * D + f]);
    Agg[(size_t)i * D + f] = ((a0 + a1) + (a2 + a3)) + ((a4 + a5) + (a6 + a7));
}

// ---- hyper phase A: M[h] = bf16(Binv[h] * sum_e G[col[e]]) ----------------

template <int K>
__global__ void k_hypA(const int* __restrict__ rp, const int* __restrict__ col,
                       const u16* __restrict__ G, const float* __restrict__ Binv,
                       u16* __restrict__ M, int nh) {
    int t = blockIdx.x * blockDim.x + threadIdx.x;
    int i = t >> 6, f = t & 63;
    if (i >= nh) return;
    int e0 = __builtin_amdgcn_readfirstlane(rp[i]);
    int e1 = __builtin_amdgcn_readfirstlane(rp[i + 1]);
    float a0 = 0.f, a1 = 0.f, a2 = 0.f, a3 = 0.f, a4 = 0.f, a5 = 0.f, a6 = 0.f, a7 = 0.f;
    int e = e0;
    for (; e + 8 <= e1; e += 8) {
        int s0 = col[e], s1 = col[e + 1], s2 = col[e + 2], s3 = col[e + 3];
        int s4 = col[e + 4], s5 = col[e + 5], s6 = col[e + 6], s7 = col[e + 7];
        a0 += bf2f(G[(size_t)s0 * K + f]);
        a1 += bf2f(G[(size_t)s1 * K + f]);
        a2 += bf2f(G[(size_t)s2 * K + f]);
        a3 += bf2f(G[(size_t)s3 * K + f]);
        a4 += bf2f(G[(size_t)s4 * K + f]);
        a5 += bf2f(G[(size_t)s5 * K + f]);
        a6 += bf2f(G[(size_t)s6 * K + f]);
        a7 += bf2f(G[(size_t)s7 * K + f]);
    }
    if (e + 4 <= e1) {
        int s0 = col[e], s1 = col[e + 1], s2 = col[e + 2], s3 = col[e + 3];
        a0 += bf2f(G[(size_t)s0 * K + f]);
        a1 += bf2f(G[(size_t)s1 * K + f]);
        a2 += bf2f(G[(size_t)s2 * K + f]);
        a3 += bf2f(G[(size_t)s3 * K + f]);
        e += 4;
    }
    for (; e < e1; ++e) a0 += bf2f(G[(size_t)col[e] * K + f]);
    if ((K == 64) || (f < K))
        M[(size_t)i * K + f] =
            f2bf((((a0 + a1) + (a2 + a3)) + ((a4 + a5) + (a6 + a7))) * Binv[i]);
}

// ---- hyper phase B: out[i] = relu?(Dinv[i] * sum_e M[col[e]] + b) ---------

template <int K, bool RELU, bool OUTBF>
__global__ void k_hypB(const int* __restrict__ rp, const int* __restrict__ col,
                       const u16* __restrict__ M, const float* __restrict__ Dinv,
                       const float* __restrict__ b, void* __restrict__ out, int n) {
    int t = blockIdx.x * blockDim.x + threadIdx.x;
    int i = t >> 6, f = t & 63;
    if (i >= n) return;
    int e0 = __builtin_amdgcn_readfirstlane(rp[i]);
    int e1 = __builtin_amdgcn_readfirstlane(rp[i + 1]);
    float a0 = 0.f, a1 = 0.f, a2 = 0.f, a3 = 0.f, a4 = 0.f, a5 = 0.f, a6 = 0.f, a7 = 0.f;
    int e = e0;
    for (; e + 8 <= e1; e += 8) {
        int s0 = col[e], s1 = col[e + 1], s2 = col[e + 2], s3 = col[e + 3];
        int s4 = col[e + 4], s5 = col[e + 5], s6 = col[e + 6], s7 = col[e + 7];
        a0 += bf2f(M[(size_t)s0 * K + f]);
        a1 += bf2f(M[(size_t)s1 * K + f]);
        a2 += bf2f(M[(size_t)s2 * K + f]);
        a3 += bf2f(M[(size_t)s3 * K + f]);
        a4 += bf2f(M[(size_t)s4 * K + f]);
        a5 += bf2f(M[(size_t)s5 * K + f]);
        a6 += bf2f(M[(size_t)s6 * K + f]);
        a7 += bf2f(M[(size_t)s7 * K + f]);
    }
    if (e + 4 <= e1) {
        int s0 = col[e], s1 = col[e + 1], s2 = col[e + 2], s3 = col[e + 3];
        a0 += bf2f(M[(size_t)s0 * K + f]);
        a1 += bf2f(M[(size_t)s1 * K + f]);
        a2 += bf2f(M[(size_t)s2 * K + f]);
        a3 += bf2f(M[(size_t)s3 * K + f]);
        e += 4;
    }
    for (; e < e1; ++e) a0 += bf2f(M[(size_t)col[e] * K + f]);
    if ((K == 64) || (f < K)) {
        float v = (((a0 + a1) + (a2 + a3)) + ((a4 + a5) + (a6 + a7))) * Dinv[i] + b[f];
        if (RELU) v = fmaxf(v, 0.0f);
        if (OUTBF) ((u16*)out)[(size_t)i * K + f] = f2bf(v);
        else       ((float*)out)[(size_t)i * K + f] = v;
    }
}

// ---- branch attention (K = 40, bf16 in) + log_softmax -> f32 --------------

__global__ void k_attn_lsm(const u16* __restrict__ X, const u16* __restrict__ Xh,
                           const float* __restrict__ w, float* __restrict__ out, int n) {
    int t = blockIdx.x * blockDim.x + threadIdx.x;
    int node = t >> 6, lane = t & 63;
    if (node >= n) return;
    bool act = lane < C;
    int idx = node * C + lane;
    float xv = act ? bf2f(X[idx]) : 0.0f;
    float hv = act ? bf2f(Xh[idx]) : 0.0f;
    float p0 = act ? xv * w[2 * lane + 0] : 0.0f;
    float p1 = act ? hv * w[2 * lane + 1] : 0.0f;
#pragma unroll
    for (int o = 32; o; o >>= 1) {
        p0 += __shfl_xor(p0, o, 64);
        p1 += __shfl_xor(p1, o, 64);
    }
    float m = fmaxf(p0, p1);
    float e0 = expf(p0 - m), e1 = expf(p1 - m);
    float inv = 1.0f / (e0 + e1);
    float v = (e0 * xv + e1 * hv) * inv;

    float mv = act ? v : -1e30f;
#pragma unroll
    for (int o = 32; o; o >>= 1) mv = fmaxf(mv, __shfl_xor(mv, o, 64));
    float ex = act ? expf(v - mv) : 0.0f;
    float s = ex;
#pragma unroll
    for (int o = 32; o; o >>= 1) s += __shfl_xor(s, o, 64);
    float lse = mv + logf(s);
    if (act) out[idx] = v - lse;
}

}  // namespace

extern "C" void kernel_launch(void* const* d_in, const int* in_sizes, int n_in,
                              void* d_out, int out_size, void* d_ws, size_t ws_size,
                              hipStream_t stream) {
    const float* x     = (const float*)d_in[0];
    const int*   ei    = (const int*)d_in[1];
    const int*   esrc  = ei;
    const int*   edst  = ei + NE;
    const int*   hnode = (const int*)d_in[2];
    const int*   hid   = (const int*)d_in[3];
    const float* W1g = (const float*)d_in[4];
    const float* b1g = (const float*)d_in[5];
    const float* W1h = (const float*)d_in[6];
    const float* b1h = (const float*)d_in[7];
    const float* aw1 = (const float*)d_in[8];
    const float* W2g = (const float*)d_in[9];
    const float* b2g = (const float*)d_in[10];
    const float* W2h = (const float*)d_in[11];
    const float* b2h = (const float*)d_in[12];
    const float* aw2 = (const float*)d_in[13];
    float* out = (float*)d_out;

    char* ws = (char*)d_ws;
    size_t off = 0;
    auto alloc = [&](size_t bytes) -> void* {
        void* p = (void*)(ws + off);
        off = (off + bytes + 255) & ~(size_t)255;
        return p;
    };
    float* dinv   = (float*)alloc((size_t)NN * 4);
    float* Binv   = (float*)alloc((size_t)NH * 4);
    float* Dinv   = (float*)alloc((size_t)NN * 4);
    int*   rpAll  = (int*)alloc((size_t)(NT + 1) * 4);
    int*   colAll = (int*)alloc((size_t)(NE + 2 * (size_t)NI) * 4);  // 14.4 MB
    int*   gcur   = (int*)alloc((size_t)NBUKT * 4);
    // union region: pairs slack (22.5 MB, build-time) / A16,X1,XH16 (38.4 MB)
    char*  U      = (char*)alloc((size_t)3 * NN * D * 2);
    u32*   pairs  = (u32*)U;
    u16*   A16    = (u16*)U;                               // also holds G2 (40-wide)
    u16*   X1     = (u16*)(U + (size_t)NN * D * 2);
    u16*   XH16   = (u16*)(U + (size_t)2 * NN * D * 2);
    u16*   M16    = (u16*)alloc((size_t)NH * D * 2);       // 1.28 MB
    float* Aggf   = (float*)alloc((size_t)NH * D * 4);     // 2.56 MB
    u16*   G4     = (u16*)alloc((size_t)NN * C * 2);       // 8 MB
    u16*   X2b    = (u16*)alloc((size_t)NN * C * 2);       // 8 MB
    u16*   XH2b   = (u16*)alloc((size_t)NN * C * 2);       // 8 MB

    const int B = 256;
    int gNN  = (NN + 255) / 256;
    int gNH  = (NH + 255) / 256;
    int gN64 = NN * 64 / 256;          // 25000 blocks, 1 wave per node
    int gH64 = NH * 64 / 256;          // 2500

    // ---- build CSR + degrees ----
    hipMemsetAsync(gcur, 0, (size_t)NBUKT * 4, stream);
    k_build<<<3 * NBLK, B, 0, stream>>>(esrc, edst, hid, hnode, gcur, pairs);
    k_p3<<<NBUKT, B, 0, stream>>>(pairs, gcur, rpAll, colAll, dinv, Binv, Dinv);

    // ---- layer 1 GCN: x1 = relu(dinv*(self + gather) + b1g) ----
    k_gemm<64, true, false><<<gNN, B, 0, stream>>>(x, W1g, dinv, A16, NN);
    k_gcn_gather<64, true, true><<<gN64, B, 0, stream>>>(rpAll, colAll, A16, dinv, b1g, X1, NN);

    // ---- layer 1 hypergraph (aggregate-first): M = (sum X1)@W1h * Binv ----
    k_hyp_agg<<<gH64, B, 0, stream>>>(rpAll + OFF_H, colAll, X1, Aggf, NH);
    k_gemm<64, true, false><<<gNH, B, 0, stream>>>(Aggf, W1h, Binv, M16, NH);
    k_hypB<64, true, true><<<gN64, B, 0, stream>>>(rpAll + OFF_N, colAll, M16, Dinv, b1h, XH16, NN);

    // ---- layer 2 GEMMs (separate launches, low VGPR each) ----
    k_gemm<40, false, true><<<gNN, B, 0, stream>>>(XH16, W2h, nullptr, G4, NN);
    k_gemm_attn<<<gNN, B, 0, stream>>>(X1, XH16, aw1, W2g, dinv, A16, NN);

    // ---- layer 2 GCN gather ----
    k_gcn_gather<40, false, true><<<gN64, B, 0, stream>>>(rpAll, colAll, A16, dinv, b2g, X2b, NN);

    // ---- layer 2 hypergraph ----
    k_hypA<40><<<gH64, B, 0, stream>>>(rpAll + OFF_H, colAll, G4, Binv, M16, NH);
    k_hypB<40, false, true><<<gN64, B, 0, stream>>>(rpAll + OFF_N, colAll, M16, Dinv, b2h, XH2b, NN);

    // ---- attention 2 + log_softmax -> out ----
    k_attn_lsm<<<gN64, B, 0, stream>>>(X2b, XH2b, aw2, out, NN);
}

// Round 10
// 374.176 us; speedup vs baseline: 1.3872x; 1.0990x over previous
//
#include <hip/hip_runtime.h>
#include <math.h>

namespace {

constexpr int NN = 100000;   // nodes
constexpr int NE = 1200000;  // edges
constexpr int NH = 10000;    // hyperedges
constexpr int NI = 1200000;  // incidences
constexpr int D  = 64;       // hidden dim
constexpr int C  = 40;       // classes

constexpr int OFF_H = NN;         // hyperedge rowptr offset
constexpr int OFF_N = NN + NH;    // node-incidence rowptr offset
constexpr int NT    = NN + NH + NN;

// bucket sort: rel0 = edges by dst, rel1 = incid by hyperedge, rel2 = incid by node
constexpr int NBLK   = 150;                 // partition blocks per relation
constexpr int CHUNK  = 8000;                // NI / NBLK (exact)
constexpr int NBUK1  = 196;                 // ceil(100000 / 512)
constexpr int NBUK2  = 157;                 // ceil(10000 / 64)
constexpr int NBUK3  = 196;
constexpr int NBUKT  = NBUK1 + NBUK2 + NBUK3;  // 549
constexpr int CAP    = 10240;               // slack region per bucket

using u16 = unsigned short;
using u32 = unsigned int;

__device__ __forceinline__ float bf2f(u16 u) {
    u32 v = (u32)u << 16;
    return __builtin_bit_cast(float, v);
}
__device__ __forceinline__ u16 f2bf(float f) {
    u32 u = __builtin_bit_cast(u32, f);
    return (u16)((u + 0x7FFFu + ((u >> 16) & 1u)) >> 16);
}
__device__ __forceinline__ u32 pack2(float a, float b) {
    return (u32)f2bf(a) | ((u32)f2bf(b) << 16);
}
__device__ __forceinline__ float bfu32(u32 w, int hi) {
    return __builtin_bit_cast(float, hi ? (w & 0xFFFF0000u) : (w << 16));
}

// ---- BUILD: LDS multisplit -> coalesced per-bucket-run writes -------------

__global__ __launch_bounds__(256) void k_build(const int* __restrict__ esrc,
                                               const int* __restrict__ edst,
                                               const int* __restrict__ hid,
                                               const int* __restrict__ hnode,
                                               int* __restrict__ gcur,
                                               u32* __restrict__ pairs) {
    int rel = blockIdx.x / NBLK, blk = blockIdx.x % NBLK;
    const int *keys, *vals;
    if (rel == 0)      { keys = edst;  vals = esrc;  }
    else if (rel == 1) { keys = hid;   vals = hnode; }
    else               { keys = hnode; vals = hid;   }
    int bukBase = rel == 0 ? 0 : (rel == 1 ? NBUK1 : NBUK1 + NBUK2);
    int nbuk    = rel == 1 ? NBUK2 : NBUK1;
    int shift   = rel == 1 ? 6 : 9;
    int mask    = (1 << shift) - 1;

    __shared__ int h[NBUK1];          // hist, then reused as cursor
    __shared__ int lofs[NBUK1 + 1];   // exclusive scan of hist
    __shared__ int gbase[NBUK1];      // reserved global offset per bucket
    __shared__ u32 stage[CHUNK];      // 32 KB bucket-sorted staging

    int tid = threadIdx.x;
    for (int i = tid; i < nbuk; i += 256) h[i] = 0;
    __syncthreads();

    int start = blk * CHUNK;
    const int4* k4 = reinterpret_cast<const int4*>(keys + start);
    const int4* v4 = reinterpret_cast<const int4*>(vals + start);

    for (int i = tid; i < CHUNK / 4; i += 256) {
        int4 kk = k4[i];
        atomicAdd(&h[kk.x >> shift], 1);
        atomicAdd(&h[kk.y >> shift], 1);
        atomicAdd(&h[kk.z >> shift], 1);
        atomicAdd(&h[kk.w >> shift], 1);
    }
    __syncthreads();

    if (tid < 64) {
        int acc = 0;
        for (int base = 0; base < nbuk; base += 64) {
            int idx = base + tid;
            int v = idx < nbuk ? h[idx] : 0;
            int sc = v;
#pragma unroll
            for (int o = 1; o < 64; o <<= 1) {
                int t = __shfl_up(sc, o, 64);
                if (tid >= o) sc += t;
            }
            if (idx < nbuk) lofs[idx] = acc + sc - v;
            acc += __shfl(sc, 63, 64);
        }
        if (tid == 0) lofs[nbuk] = acc;  // == CHUNK
    }
    __syncthreads();

    for (int i = tid; i < nbuk; i += 256) gbase[i] = atomicAdd(&gcur[bukBase + i], h[i]);
    __syncthreads();
    for (int i = tid; i < nbuk; i += 256) h[i] = lofs[i];
    __syncthreads();

    for (int i = tid; i < CHUNK / 4; i += 256) {
        int4 kk = k4[i];
        int4 vv = v4[i];
        int p0 = atomicAdd(&h[kk.x >> shift], 1);
        stage[p0] = ((u32)(kk.x & mask) << 17) | (u32)vv.x;
        int p1 = atomicAdd(&h[kk.y >> shift], 1);
        stage[p1] = ((u32)(kk.y & mask) << 17) | (u32)vv.y;
        int p2 = atomicAdd(&h[kk.z >> shift], 1);
        stage[p2] = ((u32)(kk.z & mask) << 17) | (u32)vv.z;
        int p3 = atomicAdd(&h[kk.w >> shift], 1);
        stage[p3] = ((u32)(kk.w & mask) << 17) | (u32)vv.w;
    }
    __syncthreads();

    int wid = tid >> 6, lane = tid & 63;
    for (int buk = wid; buk < nbuk; buk += 4) {
        int s0 = lofs[buk], s1 = lofs[buk + 1];
        int gb = gbase[buk];
        u32* dst = pairs + (size_t)(bukBase + buk) * CAP + gb;
        int cnt = s1 - s0;
        if (gb + cnt > CAP) cnt = CAP - gb;  // defensive
        for (int j = lane; j < cnt; j += 64) dst[j] = stage[s0 + j];
    }
}

// ---- P3: per-bucket fine counting sort -> rowptr + colAll + degrees -------

__global__ __launch_bounds__(256) void k_p3(const u32* __restrict__ pairs,
                                            const int* __restrict__ totals,
                                            int* __restrict__ rowptr,
                                            int* __restrict__ colAll,
                                            float* __restrict__ dinv,
                                            float* __restrict__ Binv,
                                            float* __restrict__ Dinv) {
    int g = blockIdx.x;
    int rel, lb;
    if (g < NBUK1)              { rel = 0; lb = g; }
    else if (g < NBUK1 + NBUK2) { rel = 1; lb = g - NBUK1; }
    else                        { rel = 2; lb = g - NBUK1 - NBUK2; }
    int shift   = rel == 1 ? 6 : 9;
    int bpb     = rel == 1 ? 64 : 512;
    int binBase = rel == 0 ? 0 : (rel == 1 ? NN : NN + NH);
    int nbins   = rel == 1 ? NH : NN;
    int keyBase = lb << shift;
    int tid = threadIdx.x;
    int lane = tid & 63, wid = tid >> 6;

    __shared__ int wred[4];
    int partial = 0;
    for (int j = tid; j < g; j += 256) partial += totals[j];
#pragma unroll
    for (int o = 32; o; o >>= 1) partial += __shfl_xor(partial, o, 64);
    if (lane == 0) wred[wid] = partial;
    __syncthreads();
    int e0 = wred[0] + wred[1] + wred[2] + wred[3];
    int cntT = totals[g];
    if (g == NBUKT - 1 && tid == 0) rowptr[NT] = e0 + cntT;

    const u32* pb = pairs + (size_t)g * CAP;

    __shared__ int h[512];
    __shared__ int cur[512];
    __shared__ int wsum[4];
    for (int i = tid; i < 512; i += 256) h[i] = 0;
    __syncthreads();
    for (int i = tid; i < cntT; i += 256)
        atomicAdd(&h[pb[i] >> 17], 1);
    __syncthreads();

    int j0 = 2 * tid;
    int v0 = h[j0], v1 = h[j0 + 1];
    int s = v0 + v1;
    int sc = s;
#pragma unroll
    for (int o = 1; o < 64; o <<= 1) {
        int t = __shfl_up(sc, o, 64);
        if (lane >= o) sc += t;
    }
    if (lane == 63) wsum[wid] = sc;
    __syncthreads();
    int woff = 0;
    for (int w = 0; w < wid; ++w) woff += wsum[w];
    int excl = woff + sc - s;
    cur[j0] = excl;
    cur[j0 + 1] = excl + v0;
    __syncthreads();

    for (int i = tid; i < bpb; i += 256) {
        int bin = keyBase + i;
        if (bin < nbins) {
            rowptr[binBase + bin] = e0 + cur[i];
            int cnt = h[i];
            if (rel == 0)      dinv[bin] = rsqrtf((float)cnt + 1.0f);
            else if (rel == 1) Binv[bin] = cnt > 0 ? 1.0f / (float)cnt : 0.0f;
            else               Dinv[bin] = cnt > 0 ? 1.0f / (float)cnt : 0.0f;
        }
    }
    __syncthreads();

    for (int i = tid; i < cntT; i += 256) {
        u32 p = pb[i];
        int pos = atomicAdd(&cur[p >> 17], 1);
        colAll[e0 + pos] = (int)(p & 0x1FFFFu);
    }
}

// ---- streaming GEMM, column-split: SPLIT threads/row, K/SPLIT cols each ----
// Y[r][cb..cb+CPT) = (sum_k X[r][k] * W[k][cb+j]) * scale?[r] -> bf16

template <int K, int SPLIT, bool SCALE, bool INBF>
__global__ __launch_bounds__(256) void k_gemm(const void* __restrict__ Xv,
                                              const float* __restrict__ W,
                                              const float* __restrict__ scale,
                                              u16* __restrict__ Y, int n) {
    constexpr int CPT = K / SPLIT;
    __shared__ float Wl[D * K];
    for (int i = threadIdx.x; i < D * K / 4; i += 256)
        reinterpret_cast<float4*>(Wl)[i] = reinterpret_cast<const float4*>(W)[i];
    __syncthreads();

    int t = blockIdx.x * 256 + threadIdx.x;
    int r = t / SPLIT, part = t % SPLIT;
    if (r >= n) return;
    int cb = part * CPT;

    float acc[CPT];
#pragma unroll
    for (int c = 0; c < CPT; ++c) acc[c] = 0.0f;

    if (INBF) {
        const uint4* x4 = reinterpret_cast<const uint4*>((const u16*)Xv + (size_t)r * D);
#pragma unroll
        for (int i = 0; i < D / 8; ++i) {
            uint4 v = x4[i];
#pragma unroll
            for (int j = 0; j < 8; ++j) {
                u32 w = (j >> 1) == 0 ? v.x : ((j >> 1) == 1 ? v.y : ((j >> 1) == 2 ? v.z : v.w));
                float xv = bfu32(w, j & 1);
                int k = 8 * i + j;
#pragma unroll
                for (int c = 0; c < CPT; ++c)
                    acc[c] = fmaf(xv, Wl[k * K + cb + c], acc[c]);
            }
        }
    } else {
        const float4* x4 = reinterpret_cast<const float4*>((const float*)Xv + (size_t)r * D);
#pragma unroll
        for (int i = 0; i < D / 4; ++i) {
            float4 v = x4[i];
#pragma unroll
            for (int j = 0; j < 4; ++j) {
                float xv = j == 0 ? v.x : (j == 1 ? v.y : (j == 2 ? v.z : v.w));
                int k = 4 * i + j;
#pragma unroll
                for (int c = 0; c < CPT; ++c)
                    acc[c] = fmaf(xv, Wl[k * K + cb + c], acc[c]);
            }
        }
    }

    float s = SCALE ? scale[r] : 1.0f;
    u32* yp = reinterpret_cast<u32*>(Y + (size_t)r * K + cb);
#pragma unroll
    for (int j = 0; j < CPT / 2; ++j)
        yp[j] = pack2(acc[2 * j] * s, acc[2 * j + 1] * s);
}

// ---- attention GEMM, two-pass streaming, column-split 4 -------------------
//      G2 = (attn(X1,XH,aw) @ W2g) * dinv -> bf16

__global__ __launch_bounds__(256) void k_gemm_attn(const u16* __restrict__ X1,
                                                   const u16* __restrict__ XH,
                                                   const float* __restrict__ aw,
                                                   const float* __restrict__ W,
                                                   const float* __restrict__ scale,
                                                   u16* __restrict__ Y, int n) {
    constexpr int SPLIT = 4, CPT = C / SPLIT;  // 10
    __shared__ float Wl[D * C];
    __shared__ float awl[2 * D];
    for (int i = threadIdx.x; i < D * C / 4; i += 256)
        reinterpret_cast<float4*>(Wl)[i] = reinterpret_cast<const float4*>(W)[i];
    for (int i = threadIdx.x; i < 2 * D; i += 256) awl[i] = aw[i];
    __syncthreads();

    int t = blockIdx.x * 256 + threadIdx.x;
    int r = t / SPLIT, part = t % SPLIT;
    if (r >= n) return;
    int cb = part * CPT;

    const uint4* x4 = reinterpret_cast<const uint4*>(X1 + (size_t)r * D);
    const uint4* h4 = reinterpret_cast<const uint4*>(XH + (size_t)r * D);

    // pass 1: attention logits (redundant per part; 2 accumulators)
    float s0 = 0.0f, s1 = 0.0f;
#pragma unroll
    for (int i = 0; i < D / 8; ++i) {
        uint4 v = x4[i];
        uint4 u = h4[i];
#pragma unroll
        for (int j = 0; j < 4; ++j) {
            u32 wv = j == 0 ? v.x : (j == 1 ? v.y : (j == 2 ? v.z : v.w));
            u32 wu = j == 0 ? u.x : (j == 1 ? u.y : (j == 2 ? u.z : u.w));
            int k = 8 * i + 2 * j;
            s0 = fmaf(bfu32(wv, 0), awl[2 * k + 0], s0);
            s0 = fmaf(bfu32(wv, 1), awl[2 * k + 2], s0);
            s1 = fmaf(bfu32(wu, 0), awl[2 * k + 1], s1);
            s1 = fmaf(bfu32(wu, 1), awl[2 * k + 3], s1);
        }
    }
    float m = fmaxf(s0, s1);
    float e0 = expf(s0 - m), e1 = expf(s1 - m);
    float inv = 1.0f / (e0 + e1);
    float a0 = e0 * inv, a1 = e1 * inv;

    // pass 2: blended row -> GEMM columns [cb, cb+CPT)
    float acc[CPT];
#pragma unroll
    for (int c = 0; c < CPT; ++c) acc[c] = 0.0f;
#pragma unroll
    for (int i = 0; i < D / 8; ++i) {
        uint4 v = x4[i];
        uint4 u = h4[i];
#pragma unroll
        for (int j = 0; j < 8; ++j) {
            u32 wv = (j >> 1) == 0 ? v.x : ((j >> 1) == 1 ? v.y : ((j >> 1) == 2 ? v.z : v.w));
            u32 wu = (j >> 1) == 0 ? u.x : ((j >> 1) == 1 ? u.y : ((j >> 1) == 2 ? u.z : u.w));
            float xa = a0 * bfu32(wv, j & 1) + a1 * bfu32(wu, j & 1);
            int k = 8 * i + j;
#pragma unroll
            for (int c = 0; c < CPT; ++c)
                acc[c] = fmaf(xa, Wl[k * C + cb + c], acc[c]);
        }
    }
    float s = scale[r];
    u32* yp = reinterpret_cast<u32*>(Y + (size_t)r * C + cb);
#pragma unroll
    for (int j = 0; j < CPT / 2; ++j)
        yp[j] = pack2(acc[2 * j] * s, acc[2 * j + 1] * s);
}

// ---- GCN gather+finalize (bf16 sources, f32 acc, 8x unrolled) -------------

template <int K, bool RELU, bool OUTBF>
__global__ void k_gcn_gather(const int* __restrict__ rp, const int* __restrict__ col,
                             const u16* __restrict__ G, const float* __restrict__ dinv,
                             const float* __restrict__ b, void* __restrict__ out, int n) {
    int t = blockIdx.x * blockDim.x + threadIdx.x;
    int i = t >> 6, f = t & 63;
    if (i >= n) return;
    int e0 = __builtin_amdgcn_readfirstlane(rp[i]);
    int e1 = __builtin_amdgcn_readfirstlane(rp[i + 1]);
    float a0 = bf2f(G[(size_t)i * K + f]);  // self loop
    float a1 = 0.f, a2 = 0.f, a3 = 0.f, a4 = 0.f, a5 = 0.f, a6 = 0.f, a7 = 0.f;
    int e = e0;
    for (; e + 8 <= e1; e += 8) {
        int s0 = col[e], s1 = col[e + 1], s2 = col[e + 2], s3 = col[e + 3];
        int s4 = col[e + 4], s5 = col[e + 5], s6 = col[e + 6], s7 = col[e + 7];
        a0 += bf2f(G[(size_t)s0 * K + f]);
        a1 += bf2f(G[(size_t)s1 * K + f]);
        a2 += bf2f(G[(size_t)s2 * K + f]);
        a3 += bf2f(G[(size_t)s3 * K + f]);
        a4 += bf2f(G[(size_t)s4 * K + f]);
        a5 += bf2f(G[(size_t)s5 * K + f]);
        a6 += bf2f(G[(size_t)s6 * K + f]);
        a7 += bf2f(G[(size_t)s7 * K + f]);
    }
    if (e + 4 <= e1) {
        int s0 = col[e], s1 = col[e + 1], s2 = col[e + 2], s3 = col[e + 3];
        a0 += bf2f(G[(size_t)s0 * K + f]);
        a1 += bf2f(G[(size_t)s1 * K + f]);
        a2 += bf2f(G[(size_t)s2 * K + f]);
        a3 += bf2f(G[(size_t)s3 * K + f]);
        e += 4;
    }
    for (; e < e1; ++e) a0 += bf2f(G[(size_t)col[e] * K + f]);
    if ((K == 64) || (f < K)) {
        float v = dinv[i] * (((a0 + a1) + (a2 + a3)) + ((a4 + a5) + (a6 + a7))) + b[f];
        if (RELU) v = fmaxf(v, 0.0f);
        if (OUTBF) ((u16*)out)[(size_t)i * K + f] = f2bf(v);
        else       ((float*)out)[(size_t)i * K + f] = v;
    }
}

// ---- hyper aggregate (layer 1): Agg[h] = sum_e X1[col[e]]  (f32 out) ------

__global__ void k_hyp_agg(const int* __restrict__ rp, const int* __restrict__ col,
                          const u16* __restrict__ G, float* __restrict__ Agg, int nh) {
    int t = blockIdx.x * blockDim.x + threadIdx.x;
    int i = t >> 6, f = t & 63;
    if (i >= nh) return;
    int e0 = __builtin_amdgcn_readfirstlane(rp[i]);
    int e1 = __builtin_amdgcn_readfirstlane(rp[i + 1]);
    float a0 = 0.f, a1 = 0.f, a2 = 0.f, a3 = 0.f, a4 = 0.f, a5 = 0.f, a6 = 0.f, a7 = 0.f;
    int e = e0;
    for (; e + 8 <= e1; e += 8) {
        int s0 = col[e], s1 = col[e + 1], s2 = col[e + 2], s3 = col[e + 3];
        int s4 = col[e + 4], s5 = col[e + 5], s6 = col[e + 6], s7 = col[e + 7];
        a0 += bf2f(G[(size_t)s0 * D + f]);
        a1 += bf2f(G[(size_t)s1 * D + f]);
        a2 += bf2f(G[(size_t)s2 * D + f]);
        a3 += bf2f(G[(size_t)s3 * D + f]);
        a4 += bf2f(G[(size_t)s4 * D + f]);
        a5 += bf2f(G[(size_t)s5 * D + f]);
        a6 += bf2f(G[(size_t)s6 * D + f]);
        a7 += bf2f(G[(size_t)s7 * D + f]);
    }
    if (e + 4 <= e1) {
        int s0 = col[e], s1 = col[e + 1], s2 = col[e + 2], s3 = col[e + 3];
        a0 += bf2f(G[(size_t)s0 * D + f]);
        a1 += bf2f(G[(size_t)s1 * D + f]);
        a2 += bf2f(G[(size_t)s2 * D + f]);
        a3 += bf2f(G[(size_t)s3 * D + f]);
        e += 4;
    }
    for (; e < e1; ++e) a0 += bf2f(G[(size_t)col[e] * D + f]);
    Agg[(size_t)i * D + f] = ((a0 + a1) + (a2 + a3)) + ((a4 + a5) + (a6 + a7));
}

// ---- hyper phase A: M[h] = bf16(Binv[h] * sum_e G[col[e]]) ----------------

template <int K>
__global__ void k_hypA(const int* __restrict__ rp, const int* __restrict__ col,
                       const u16* __restrict__ G, const float* __restrict__ Binv,
                       u16* __restrict__ M, int nh) {
    int t = blockIdx.x * blockDim.x + threadIdx.x;
    int i = t >> 6, f = t & 63;
    if (i >= nh) return;
    int e0 = __builtin_amdgcn_readfirstlane(rp[i]);
    int e1 = __builtin_amdgcn_readfirstlane(rp[i + 1]);
    float a0 = 0.f, a1 = 0.f, a2 = 0.f, a3 = 0.f, a4 = 0.f, a5 = 0.f, a6 = 0.f, a7 = 0.f;
    int e = e0;
    for (; e + 8 <= e1; e += 8) {
        int s0 = col[e], s1 = col[e + 1], s2 = col[e + 2], s3 = col[e + 3];
        int s4 = col[e + 4], s5 = col[e + 5], s6 = col[e + 6], s7 = col[e + 7];
        a0 += bf2f(G[(size_t)s0 * K + f]);
        a1 += bf2f(G[(size_t)s1 * K + f]);
        a2 += bf2f(G[(size_t)s2 * K + f]);
        a3 += bf2f(G[(size_t)s3 * K + f]);
        a4 += bf2f(G[(size_t)s4 * K + f]);
        a5 += bf2f(G[(size_t)s5 * K + f]);
        a6 += bf2f(G[(size_t)s6 * K + f]);
        a7 += bf2f(G[(size_t)s7 * K + f]);
    }
    if (e + 4 <= e1) {
        int s0 = col[e], s1 = col[e + 1], s2 = col[e + 2], s3 = col[e + 3];
        a0 += bf2f(G[(size_t)s0 * K + f]);
        a1 += bf2f(G[(size_t)s1 * K + f]);
        a2 += bf2f(G[(size_t)s2 * K + f]);
        a3 += bf2f(G[(size_t)s3 * K + f]);
        e += 4;
    }
    for (; e < e1; ++e) a0 += bf2f(G[(size_t)col[e] * K + f]);
    if ((K == 64) || (f < K))
        M[(size_t)i * K + f] =
            f2bf((((a0 + a1) + (a2 + a3)) + ((a4 + a5) + (a6 + a7))) * Binv[i]);
}

// ---- hyper phase B: out[i] = relu?(Dinv[i] * sum_e M[col[e]] + b) ---------

template <int K, bool RELU, bool OUTBF>
__global__ void k_hypB(const int* __restrict__ rp, const int* __restrict__ col,
                       const u16* __restrict__ M, const float* __restrict__ Dinv,
                       const float* __restrict__ b, void* __restrict__ out, int n) {
    int t = blockIdx.x * blockDim.x + threadIdx.x;
    int i = t >> 6, f = t & 63;
    if (i >= n) return;
    int e0 = __builtin_amdgcn_readfirstlane(rp[i]);
    int e1 = __builtin_amdgcn_readfirstlane(rp[i + 1]);
    float a0 = 0.f, a1 = 0.f, a2 = 0.f, a3 = 0.f, a4 = 0.f, a5 = 0.f, a6 = 0.f, a7 = 0.f;
    int e = e0;
    for (; e + 8 <= e1; e += 8) {
        int s0 = col[e], s1 = col[e + 1], s2 = col[e + 2], s3 = col[e + 3];
        int s4 = col[e + 4], s5 = col[e + 5], s6 = col[e + 6], s7 = col[e + 7];
        a0 += bf2f(M[(size_t)s0 * K + f]);
        a1 += bf2f(M[(size_t)s1 * K + f]);
        a2 += bf2f(M[(size_t)s2 * K + f]);
        a3 += bf2f(M[(size_t)s3 * K + f]);
        a4 += bf2f(M[(size_t)s4 * K + f]);
        a5 += bf2f(M[(size_t)s5 * K + f]);
        a6 += bf2f(M[(size_t)s6 * K + f]);
        a7 += bf2f(M[(size_t)s7 * K + f]);
    }
    if (e + 4 <= e1) {
        int s0 = col[e], s1 = col[e + 1], s2 = col[e + 2], s3 = col[e + 3];
        a0 += bf2f(M[(size_t)s0 * K + f]);
        a1 += bf2f(M[(size_t)s1 * K + f]);
        a2 += bf2f(M[(size_t)s2 * K + f]);
        a3 += bf2f(M[(size_t)s3 * K + f]);
        e += 4;
    }
    for (; e < e1; ++e) a0 += bf2f(M[(size_t)col[e] * K + f]);
    if ((K == 64) || (f < K)) {
        float v = (((a0 + a1) + (a2 + a3)) + ((a4 + a5) + (a6 + a7))) * Dinv[i] + b[f];
        if (RELU) v = fmaxf(v, 0.0f);
        if (OUTBF) ((u16*)out)[(size_t)i * K + f] = f2bf(v);
        else       ((float*)out)[(size_t)i * K + f] = v;
    }
}

// ---- branch attention (K = 40, bf16 in) + log_softmax -> f32 --------------

__global__ void k_attn_lsm(const u16* __restrict__ X, const u16* __restrict__ Xh,
                           const float* __restrict__ w, float* __restrict__ out, int n) {
    int t = blockIdx.x * blockDim.x + threadIdx.x;
    int node = t >> 6, lane = t & 63;
    if (node >= n) return;
    bool act = lane < C;
    int idx = node * C + lane;
    float xv = act ? bf2f(X[idx]) : 0.0f;
    float hv = act ? bf2f(Xh[idx]) : 0.0f;
    float p0 = act ? xv * w[2 * lane + 0] : 0.0f;
    float p1 = act ? hv * w[2 * lane + 1] : 0.0f;
#pragma unroll
    for (int o = 32; o; o >>= 1) {
        p0 += __shfl_xor(p0, o, 64);
        p1 += __shfl_xor(p1, o, 64);
    }
    float m = fmaxf(p0, p1);
    float e0 = expf(p0 - m), e1 = expf(p1 - m);
    float inv = 1.0f / (e0 + e1);
    float v = (e0 * xv + e1 * hv) * inv;

    float mv = act ? v : -1e30f;
#pragma unroll
    for (int o = 32; o; o >>= 1) mv = fmaxf(mv, __shfl_xor(mv, o, 64));
    float ex = act ? expf(v - mv) : 0.0f;
    float s = ex;
#pragma unroll
    for (int o = 32; o; o >>= 1) s += __shfl_xor(s, o, 64);
    float lse = mv + logf(s);
    if (act) out[idx] = v - lse;
}

}  // namespace

extern "C" void kernel_launch(void* const* d_in, const int* in_sizes, int n_in,
                              void* d_out, int out_size, void* d_ws, size_t ws_size,
                              hipStream_t stream) {
    const float* x     = (const float*)d_in[0];
    const int*   ei    = (const int*)d_in[1];
    const int*   esrc  = ei;
    const int*   edst  = ei + NE;
    const int*   hnode = (const int*)d_in[2];
    const int*   hid   = (const int*)d_in[3];
    const float* W1g = (const float*)d_in[4];
    const float* b1g = (const float*)d_in[5];
    const float* W1h = (const float*)d_in[6];
    const float* b1h = (const float*)d_in[7];
    const float* aw1 = (const float*)d_in[8];
    const float* W2g = (const float*)d_in[9];
    const float* b2g = (const float*)d_in[10];
    const float* W2h = (const float*)d_in[11];
    const float* b2h = (const float*)d_in[12];
    const float* aw2 = (const float*)d_in[13];
    float* out = (float*)d_out;

    char* ws = (char*)d_ws;
    size_t off = 0;
    auto alloc = [&](size_t bytes) -> void* {
        void* p = (void*)(ws + off);
        off = (off + bytes + 255) & ~(size_t)255;
        return p;
    };
    float* dinv   = (float*)alloc((size_t)NN * 4);
    float* Binv   = (float*)alloc((size_t)NH * 4);
    float* Dinv   = (float*)alloc((size_t)NN * 4);
    int*   rpAll  = (int*)alloc((size_t)(NT + 1) * 4);
    int*   colAll = (int*)alloc((size_t)(NE + 2 * (size_t)NI) * 4);  // 14.4 MB
    int*   gcur   = (int*)alloc((size_t)NBUKT * 4);
    // union region: pairs slack (22.5 MB, build-time) / A16,X1,XH16 (38.4 MB)
    char*  U      = (char*)alloc((size_t)3 * NN * D * 2);
    u32*   pairs  = (u32*)U;
    u16*   A16    = (u16*)U;                               // also holds G2 (40-wide)
    u16*   X1     = (u16*)(U + (size_t)NN * D * 2);
    u16*   XH16   = (u16*)(U + (size_t)2 * NN * D * 2);
    u16*   M16    = (u16*)alloc((size_t)NH * D * 2);       // 1.28 MB
    float* Aggf   = (float*)alloc((size_t)NH * D * 4);     // 2.56 MB
    u16*   G4     = (u16*)alloc((size_t)NN * C * 2);       // 8 MB
    u16*   X2b    = (u16*)alloc((size_t)NN * C * 2);       // 8 MB
    u16*   XH2b   = (u16*)alloc((size_t)NN * C * 2);       // 8 MB

    const int B = 256;
    int gN64 = NN * 64 / 256;          // 25000 blocks, 1 wave per node
    int gH64 = NH * 64 / 256;          // 2500
    int gG1  = (NN * 2 + 255) / 256;   // 782  (K=64 SPLIT=2)
    int gGH  = (NH * 4 + 255) / 256;   // 157  (K=64 SPLIT=4)
    int gG4  = (NN * 2 + 255) / 256;   // 782  (K=40 SPLIT=2)
    int gGA  = (NN * 4 + 255) / 256;   // 1563 (attn, SPLIT=4)

    // ---- build CSR + degrees ----
    hipMemsetAsync(gcur, 0, (size_t)NBUKT * 4, stream);
    k_build<<<3 * NBLK, B, 0, stream>>>(esrc, edst, hid, hnode, gcur, pairs);
    k_p3<<<NBUKT, B, 0, stream>>>(pairs, gcur, rpAll, colAll, dinv, Binv, Dinv);

    // ---- layer 1 GCN: x1 = relu(dinv*(self + gather) + b1g) ----
    k_gemm<64, 2, true, false><<<gG1, B, 0, stream>>>(x, W1g, dinv, A16, NN);
    k_gcn_gather<64, true, true><<<gN64, B, 0, stream>>>(rpAll, colAll, A16, dinv, b1g, X1, NN);

    // ---- layer 1 hypergraph (aggregate-first): M = (sum X1)@W1h * Binv ----
    k_hyp_agg<<<gH64, B, 0, stream>>>(rpAll + OFF_H, colAll, X1, Aggf, NH);
    k_gemm<64, 4, true, false><<<gGH, B, 0, stream>>>(Aggf, W1h, Binv, M16, NH);
    k_hypB<64, true, true><<<gN64, B, 0, stream>>>(rpAll + OFF_N, colAll, M16, Dinv, b1h, XH16, NN);

    // ---- layer 2 GEMMs (column-split, high occupancy) ----
    k_gemm<40, 2, false, true><<<gG4, B, 0, stream>>>(XH16, W2h, nullptr, G4, NN);
    k_gemm_attn<<<gGA, B, 0, stream>>>(X1, XH16, aw1, W2g, dinv, A16, NN);

    // ---- layer 2 GCN gather ----
    k_gcn_gather<40, false, true><<<gN64, B, 0, stream>>>(rpAll, colAll, A16, dinv, b2g, X2b, NN);

    // ---- layer 2 hypergraph ----
    k_hypA<40><<<gH64, B, 0, stream>>>(rpAll + OFF_H, colAll, G4, Binv, M16, NH);
    k_hypB<40, false, true><<<gN64, B, 0, stream>>>(rpAll + OFF_N, colAll, M16, Dinv, b2h, XH2b, NN);

    // ---- attention 2 + log_softmax -> out ----
    k_attn_lsm<<<gN64, B, 0, stream>>>(X2b, XH2b, aw2, out, NN);
}